// Round 8
// baseline (370.355 us; speedup 1.0000x reference)
//
#include <hip/hip_runtime.h>
#include <cstddef>
#include <cstdint>

constexpr int Nf = 128, Pp = 256, Dd = 256, Hh = 16, Mm = 32;
constexpr int OUTC = 512, HID = 2048, C3 = 1536;

typedef short short8 __attribute__((ext_vector_type(8)));   // 8 bf16 (4 VGPRs)
typedef float f32x4 __attribute__((ext_vector_type(4)));    // 4 fp32 acc

// fp32 -> bf16 round-to-nearest-even (scalar sites)
__device__ inline unsigned short f2bf(float f) {
  unsigned u = __float_as_uint(f);
  u += 0x7fffu + ((u >> 16) & 1u);
  return (unsigned short)(u >> 16);
}
// packed pair via HW cvt (RNE), 1 op per 2 values (T12 recipe)
__device__ inline unsigned pk2(float a, float b) {
  unsigned r;
  asm("v_cvt_pk_bf16_f32 %0, %1, %2" : "=v"(r) : "v"(a), "v"(b));
  return r;
}

// ---------------------------------------------------------------------------
__global__ __launch_bounds__(256) void conv_x(const float* __restrict__ x,
                                              short* __restrict__ xb) {
  int idx = blockIdx.x * 256 + threadIdx.x;
  const float4* s = (const float4*)x + (size_t)idx * 2;
  float4 a = s[0], c = s[1];
  uint4 o;
  o.x = pk2(a.x, a.y); o.y = pk2(a.z, a.w);
  o.z = pk2(c.x, c.y); o.w = pk2(c.z, c.w);
  ((uint4*)xb)[idx] = o;
}

// Generic coalesced transpose: in (R x C fp32, slice z) -> out (C x R bf16).
__global__ __launch_bounds__(256) void transpose_to_bf16(const float* __restrict__ in,
                                                         short* __restrict__ out,
                                                         int R, int C) {
  __shared__ float tile[64 * 65];
  const int t = threadIdx.x;
  const int rb = blockIdx.y * 64, cb = blockIdx.x * 64;
  const size_t sl = (size_t)blockIdx.z * R * C;
#pragma unroll
  for (int u = 0; u < 4; ++u) {
    int r = (t >> 4) + u * 16, c4 = (t & 15) * 4;
    float4 v = *(const float4*)(in + sl + (size_t)(rb + r) * C + cb + c4);
    tile[r * 65 + c4 + 0] = v.x;
    tile[r * 65 + c4 + 1] = v.y;
    tile[r * 65 + c4 + 2] = v.z;
    tile[r * 65 + c4 + 3] = v.w;
  }
  __syncthreads();
#pragma unroll
  for (int u = 0; u < 2; ++u) {
    int id = t + u * 256;
    int n = id >> 3, kg = id & 7;
    float a[8];
#pragma unroll
    for (int q = 0; q < 8; ++q) a[q] = tile[(kg * 8 + q) * 65 + n];
    uint4 o;
    o.x = pk2(a[0], a[1]); o.y = pk2(a[2], a[3]);
    o.z = pk2(a[4], a[5]); o.w = pk2(a[6], a[7]);
    *(uint4*)(out + sl + (size_t)(cb + n) * R + rb + kg * 8) = o;
  }
}

// B2t[c][k], k = HH*32+MM (1536 x 512)
__global__ void repack_b2t(const float* __restrict__ Wp, short* __restrict__ B2t) {
  int idx = blockIdx.x * 256 + threadIdx.x;  // 786432
  int c = idx >> 9, k = idx & 511;
  int w = c >> 9, h = (c >> 5) & 15, m = c & 31;
  int HH = k >> 5, MM = k & 31;
  B2t[idx] = (short)f2bf(Wp[(((w * Hh + h) * Mm + m) * Hh + HH) * Mm + MM]);
}

// ---------------------------------------------------------------------------
// MLP collapse helpers (run once; small).
__global__ __launch_bounds__(256) void wc_splitk(const short* __restrict__ A,   // W2t: 512 x 2048
                                                 const short* __restrict__ Bt,  // W1 bf16: 512 x 2048
                                                 float* __restrict__ part) {
  __shared__ short As[128 * 32];
  __shared__ short Bs[128 * 32];
  const int t = threadIdx.x;
  const int wv = t >> 6, ln = t & 63;
  const int wr = wv >> 1, wc = wv & 1;
  const int lr = ln & 15, kq = ln >> 4;
  const int row0 = blockIdx.y * 128, col0 = blockIdx.x * 128;
  const int k0 = blockIdx.z * 256;

  f32x4 acc[4][4];
#pragma unroll
  for (int i = 0; i < 4; ++i)
#pragma unroll
    for (int j = 0; j < 4; ++j) acc[i][j] = {0.f, 0.f, 0.f, 0.f};

  for (int kt = k0; kt < k0 + 256; kt += 32) {
#pragma unroll
    for (int u = 0; u < 2; ++u) {
      int seg = wv * 128 + u * 64 + ln;
      int r = seg >> 2, kg = seg & 3;
      const short* gp = A + (size_t)(row0 + r) * HID + kt + kg * 8;
      __builtin_amdgcn_global_load_lds(
          (const __attribute__((address_space(1))) void*)gp,
          (__attribute__((address_space(3))) void*)&As[(wv * 128 + u * 64) * 8], 16, 0, 0);
    }
#pragma unroll
    for (int u = 0; u < 2; ++u) {
      int seg = wv * 128 + u * 64 + ln;
      int r = seg >> 2, kg = seg & 3;
      const short* gp = Bt + (size_t)(col0 + r) * HID + kt + kg * 8;
      __builtin_amdgcn_global_load_lds(
          (const __attribute__((address_space(1))) void*)gp,
          (__attribute__((address_space(3))) void*)&Bs[(wv * 128 + u * 64) * 8], 16, 0, 0);
    }
    __syncthreads();
    short8 a[4], b[4];
#pragma unroll
    for (int ti = 0; ti < 4; ++ti)
      a[ti] = *(const short8*)&As[(wr * 64 + ti * 16 + lr) * 32 + kq * 8];
#pragma unroll
    for (int tj = 0; tj < 4; ++tj)
      b[tj] = *(const short8*)&Bs[(wc * 64 + tj * 16 + lr) * 32 + kq * 8];
#pragma unroll
    for (int ti = 0; ti < 4; ++ti)
#pragma unroll
      for (int tj = 0; tj < 4; ++tj)
        acc[ti][tj] = __builtin_amdgcn_mfma_f32_16x16x32_bf16(a[ti], b[tj], acc[ti][tj], 0, 0, 0);
    __syncthreads();
  }

#pragma unroll
  for (int tj = 0; tj < 4; ++tj) {
    int gcol = col0 + wc * 64 + tj * 16 + lr;
#pragma unroll
    for (int ti = 0; ti < 4; ++ti)
#pragma unroll
      for (int rg = 0; rg < 4; ++rg) {
        int grow = row0 + wr * 64 + ti * 16 + kq * 4 + rg;
        part[((size_t)blockIdx.z * 512 + grow) * 512 + gcol] = acc[ti][tj][rg];
      }
  }
}

__global__ __launch_bounds__(256) void wc_reduce(const float* __restrict__ part,
                                                 short* __restrict__ Wct) {
  int idx = blockIdx.x * 256 + threadIdx.x;  // 262144
  float s = 0.f;
#pragma unroll
  for (int z = 0; z < 8; ++z) s += part[(size_t)z * 262144 + idx];
  Wct[idx] = (short)f2bf(s);
}

__global__ __launch_bounds__(256) void bc_partial(const float* __restrict__ b1,
                                                  const float* __restrict__ W2,
                                                  float* __restrict__ part) {
  const int z = blockIdx.x;       // 64 chunks of 32 h
  const int t = threadIdx.x;
  float s0 = 0.f, s1 = 0.f;
#pragma unroll
  for (int hh = 0; hh < 32; ++hh) {
    int h = z * 32 + hh;
    float bv = b1[h];
    s0 += bv * W2[(size_t)h * OUTC + t];
    s1 += bv * W2[(size_t)h * OUTC + t + 256];
  }
  part[z * OUTC + t] = s0;
  part[z * OUTC + t + 256] = s1;
}

__global__ __launch_bounds__(256) void bc_finish(const float* __restrict__ part,
                                                 const float* __restrict__ b2,
                                                 float* __restrict__ bc) {
  int o = blockIdx.x * 256 + threadIdx.x;  // 512
  float s = b2[o];
#pragma unroll
  for (int z = 0; z < 64; ++z) s += part[z * OUTC + o];
  bc[o] = s;
}

// ---------------------------------------------------------------------------
// bf16 MFMA GEMM, counted-vmcnt 2-deep pipeline + LDS XOR swizzle (verified r5).
template <int KDIM, int NCOLS, int AMAP, int EPI, int OUTT>
__global__ __launch_bounds__(256) void gemm_mfma(const short* __restrict__ A,
                                                 const short* __restrict__ Bt,
                                                 void* __restrict__ Cv,
                                                 const float* __restrict__ bias,
                                                 int j0, int pshift, int pc) {
  __shared__ __align__(16) short SH[16384];   // As[2] | Bs[2]; reused as outb
  const int t = threadIdx.x;
  const int wv = t >> 6, ln = t & 63;
  const int wr = wv >> 1, wc = wv & 1;
  const int lr = ln & 15, kq = ln >> 4;

  constexpr int NBX = NCOLS / 128;
  constexpr int NT = KDIM / 32;
  int lin = blockIdx.y * NBX + blockIdx.x;
  int nblk = gridDim.x * gridDim.y;
  int bx, by;
  if ((nblk & 7) == 0) {
    int per = nblk >> 3;
    int id = (lin & 7) * per + (lin >> 3);   // bijective; groups rows per XCD
    bx = id % NBX; by = id / NBX;
  } else {
    bx = blockIdx.x; by = blockIdx.y;
  }
  const int row0 = by * 128, col0 = bx * 128;

  // Staging geometry (constant per thread).
  const int seg0 = wv * 128 + ln;
  const int seg1 = wv * 128 + 64 + ln;
  const int r0 = seg0 >> 2, r1 = seg1 >> 2;
  const int kg0 = (seg0 & 3) ^ ((r0 >> 1) & 3);   // pre-swizzled source chunk
  const int kg1 = (seg1 & 3) ^ ((r1 >> 1) & 3);
  size_t arow0, arow1;
  {
    int rr = row0 + r0;
    if (AMAP == 0)      arow0 = (size_t)rr;
    else if (AMAP == 3) arow0 = (size_t)(((rr & 127) << 8) + (rr >> 7));
    else { int i = rr >> pshift, jj = rr & (pc - 1); arow0 = (size_t)((i << 8) + j0 + jj); }
    rr = row0 + r1;
    if (AMAP == 0)      arow1 = (size_t)rr;
    else if (AMAP == 3) arow1 = (size_t)(((rr & 127) << 8) + (rr >> 7));
    else { int i = rr >> pshift, jj = rr & (pc - 1); arow1 = (size_t)((i << 8) + j0 + jj); }
  }
  const size_t brow0 = (size_t)(col0 + r0), brow1 = (size_t)(col0 + r1);

  auto stage = [&](int buf, int tk) {
    const int kt = tk * 32;
    __builtin_amdgcn_global_load_lds(
        (const __attribute__((address_space(1))) void*)(A + arow0 * KDIM + kt + kg0 * 8),
        (__attribute__((address_space(3))) void*)&SH[buf * 4096 + (wv * 128) * 8], 16, 0, 0);
    __builtin_amdgcn_global_load_lds(
        (const __attribute__((address_space(1))) void*)(A + arow1 * KDIM + kt + kg1 * 8),
        (__attribute__((address_space(3))) void*)&SH[buf * 4096 + (wv * 128 + 64) * 8], 16, 0, 0);
    __builtin_amdgcn_global_load_lds(
        (const __attribute__((address_space(1))) void*)(Bt + brow0 * KDIM + kt + kg0 * 8),
        (__attribute__((address_space(3))) void*)&SH[8192 + buf * 4096 + (wv * 128) * 8], 16, 0, 0);
    __builtin_amdgcn_global_load_lds(
        (const __attribute__((address_space(1))) void*)(Bt + brow1 * KDIM + kt + kg1 * 8),
        (__attribute__((address_space(3))) void*)&SH[8192 + buf * 4096 + (wv * 128 + 64) * 8], 16, 0, 0);
  };

  f32x4 acc[4][4];
#pragma unroll
  for (int i = 0; i < 4; ++i)
#pragma unroll
    for (int j = 0; j < 4; ++j) acc[i][j] = {0.f, 0.f, 0.f, 0.f};

  const int slot = kq ^ ((lr >> 1) & 3);   // swizzled fragment slot

  stage(0, 0);
  stage(1, 1);
  asm volatile("s_waitcnt vmcnt(4)" ::: "memory");
  __builtin_amdgcn_s_barrier();

  for (int tk = 0; tk < NT; ++tk) {
    const int cur = tk & 1;
    short8 a[4], b[4];
#pragma unroll
    for (int ti = 0; ti < 4; ++ti)
      a[ti] = *(const short8*)&SH[cur * 4096 + (wr * 64 + ti * 16 + lr) * 32 + slot * 8];
#pragma unroll
    for (int tj = 0; tj < 4; ++tj)
      b[tj] = *(const short8*)&SH[8192 + cur * 4096 + (wc * 64 + tj * 16 + lr) * 32 + slot * 8];
    __builtin_amdgcn_sched_barrier(0);
    asm volatile("s_waitcnt lgkmcnt(0)" ::: "memory");
    __builtin_amdgcn_sched_barrier(0);
    if (tk + 1 < NT) {
      __builtin_amdgcn_s_barrier();        // all waves done reading buf[cur]
      if (tk + 2 < NT) stage(cur, tk + 2);
    }
#pragma unroll
    for (int ti = 0; ti < 4; ++ti)
#pragma unroll
      for (int tj = 0; tj < 4; ++tj)
        acc[ti][tj] = __builtin_amdgcn_mfma_f32_16x16x32_bf16(a[ti], b[tj], acc[ti][tj], 0, 0, 0);
    if (tk + 1 < NT) {
      if (tk + 2 < NT) {
        asm volatile("s_waitcnt vmcnt(4)" ::: "memory");
      } else {
        asm volatile("s_waitcnt vmcnt(0)" ::: "memory");
      }
      __builtin_amdgcn_s_barrier();
      __builtin_amdgcn_sched_barrier(0);
    }
  }

  if (EPI == 0 || EPI == 1) {
#pragma unroll
    for (int tj = 0; tj < 4; ++tj) {
      int gcol = col0 + wc * 64 + tj * 16 + lr;
      float bv = (EPI == 0) ? bias[gcol] : 0.f;
#pragma unroll
      for (int ti = 0; ti < 4; ++ti) {
#pragma unroll
        for (int rg = 0; rg < 4; ++rg) {
          int grow = row0 + wr * 64 + ti * 16 + kq * 4 + rg;
          float val = acc[ti][tj][rg];
          if (EPI == 0) {
            val += bv;
            if (OUTT == 0) ((short*)Cv)[(size_t)grow * NCOLS + gcol] = (short)f2bf(val);
            else           ((float*)Cv)[(size_t)grow * NCOLS + gcol] = val;
          } else {
            int w = gcol >> 9, h = (gcol >> 5) & 15, m = gcol & 31;
            int i = grow >> pshift, jj = grow & (pc - 1);
            size_t addr = (((size_t)(w * Hh + h) * pc + jj) * Nf + i) * Mm + m;
            ((short*)Cv)[addr] = (short)f2bf(val);
          }
        }
      }
    }
  } else {
    // LDS-staged coalesced epilogue (EPI==2 point layout, EPI==3 temporal).
    __builtin_amdgcn_s_barrier();   // all waves done with SH (reads complete)
#pragma unroll
    for (int ti = 0; ti < 4; ++ti)
#pragma unroll
      for (int tj = 0; tj < 4; ++tj) {
        int c = wc * 64 + tj * 16 + lr;
        int q = c >> 5, m = c & 31;
#pragma unroll
        for (int rg = 0; rg < 4; ++rg) {
          int g = wr * 64 + ti * 16 + kq * 4 + rg;
          SH[q * 4096 + g * 32 + (m ^ ((g & 4) << 2))] = (short)f2bf(acc[ti][tj][rg]);
        }
      }
    __syncthreads();
#pragma unroll
    for (int u = 0; u < 8; ++u) {
      int id = u * 256 + t;
      int q = id >> 9, rem = id & 511, g = rem >> 2, mc = (rem & 3) * 8;
      uint4 v = *(const uint4*)&SH[q * 4096 + g * 32 + (mc ^ ((g & 4) << 2))];
      int gc = col0 + q * 32;
      int w = gc >> 9, h = (gc >> 5) & 15;
      size_t base;
      if (EPI == 3) base = ((size_t)(w * Hh + h) * 256 + (row0 >> 7)) * 4096;
      else          base = (((size_t)(w * Hh + h) * pc + (row0 >> 8)) * 256 + (row0 & 255)) * 32;
      *(uint4*)((short*)Cv + base + g * 32 + mc) = v;
    }
  }
}

// ---------------------------------------------------------------------------
// Temporal attention, MFMA. r8: Q fragments direct global->VGPR (no Q LDS),
// LDS 36352 B -> 4 blocks/CU; J-half-split PV (r7); swizzled K staging.
__global__ __launch_bounds__(256, 4) void temporal_attn_mfma(const short* __restrict__ T,
                                                             short* __restrict__ At,
                                                             int j0, int jcShift) {
  constexpr int KsO = 0, VtO = 4096, WtO = 8448, RsO = 17664;
  __shared__ __align__(16) short lds[18176];
  float* rs = (float*)&lds[RsO];
  const int JC = 1 << jcShift;
  const int h  = blockIdx.x >> jcShift;
  const int jj = blockIdx.x & (JC - 1);
  const int t  = threadIdx.x;
  const int wv = t >> 6, ln = t & 63;
  const int wr = wv >> 1, wc = wv & 1;
  const int lr = ln & 15, kq = ln >> 4;
  const size_t WC = (size_t)(Hh << jcShift) * 4096;
  const short* qb = T + (size_t)(h * JC + jj) * 4096;
  const short* kb = qb + WC;
  const short* vb = qb + 2 * WC;

  const int lnoff = (ln >> 2) * 32 + (((ln & 3) ^ ((ln >> 3) & 3)) * 8);
  const int qkslot = (kq ^ ((lr >> 1) & 3)) * 8;   // swizzled fragment slot

  // Q fragments direct from global (row-major 128x32, 16B-aligned rows).
  short8 af[4];
#pragma unroll
  for (int ti = 0; ti < 4; ++ti)
    af[ti] = *(const short8*)(qb + (wr * 64 + ti * 16 + lr) * 32 + kq * 8);

#pragma unroll
  for (int u = 0; u < 2; ++u) {
    int seg = wv * 2 + u;
    __builtin_amdgcn_global_load_lds(
        (const __attribute__((address_space(1))) void*)(kb + seg * 512 + lnoff),
        (__attribute__((address_space(3))) void*)&lds[KsO + seg * 512], 16, 0, 0);
  }
#pragma unroll
  for (int u = 0; u < 2; ++u) {
    int idx = t + u * 256;
    int I = idx >> 2, g = idx & 3;
    uint4 v = *(const uint4*)(vb + idx * 8);
    unsigned w0 = v.x, w1 = v.y, w2 = v.z, w3 = v.w;
    if (g & 1) { unsigned tp = w0; w0 = w1; w1 = w2; w2 = w3; w3 = tp; }
    if (g & 2) { unsigned t0 = w0, t1 = w1; w0 = w2; w1 = w3; w2 = t0; w3 = t1; }
    const unsigned wa[4] = {w0, w1, w2, w3};
    int m0 = g * 8, g2 = g * 2;
#pragma unroll
    for (int k = 0; k < 4; ++k) {
      int q = (2 * k + g2) & 7;
      lds[VtO + (m0 + q) * 136 + I]     = (short)(wa[k] & 0xffffu);
      lds[VtO + (m0 + q + 1) * 136 + I] = (short)(wa[k] >> 16);
    }
  }
  __syncthreads();

  short8 bf[4];
#pragma unroll
  for (int tj = 0; tj < 4; ++tj)
    bf[tj] = *(const short8*)&lds[KsO + (wc * 64 + tj * 16 + lr) * 32 + qkslot];
  f32x4 e[4][4];
#pragma unroll
  for (int ti = 0; ti < 4; ++ti)
#pragma unroll
    for (int tj = 0; tj < 4; ++tj) e[ti][tj] = {0.f, 0.f, 0.f, 0.f};
#pragma unroll
  for (int ti = 0; ti < 4; ++ti)
#pragma unroll
    for (int tj = 0; tj < 4; ++tj)
      e[ti][tj] = __builtin_amdgcn_mfma_f32_16x16x32_bf16(af[ti], bf[tj], e[ti][tj], 0, 0, 0);

  float part[4][4];
#pragma unroll
  for (int ti = 0; ti < 4; ++ti)
#pragma unroll
    for (int r = 0; r < 4; ++r) {
      float p = 0.f;
#pragma unroll
      for (int tj = 0; tj < 4; ++tj) {
        float ex = __expf(e[ti][tj][r]);
        e[ti][tj][r] = ex;
        p += ex;
      }
      part[ti][r] = p;
    }
#pragma unroll
  for (int msk = 1; msk <= 8; msk <<= 1)
#pragma unroll
    for (int ti = 0; ti < 4; ++ti)
#pragma unroll
      for (int r = 0; r < 4; ++r)
        part[ti][r] += __shfl_xor(part[ti][r], msk, 64);
  if (lr == 0) {
#pragma unroll
    for (int ti = 0; ti < 4; ++ti)
#pragma unroll
      for (int r = 0; r < 4; ++r)
        rs[wc * 128 + wr * 64 + ti * 16 + kq * 4 + r] = part[ti][r];
  }
  __syncthreads();

  // normalize all P in registers
#pragma unroll
  for (int ti = 0; ti < 4; ++ti)
#pragma unroll
    for (int r = 0; r < 4; ++r) {
      int I = wr * 64 + ti * 16 + kq * 4 + r;
      float inv = 1.f / (rs[I] + rs[128 + I]);
#pragma unroll
      for (int tj = 0; tj < 4; ++tj) e[ti][tj][r] *= inv;
    }

  // J-half-split PV: phase p uses Wt rows [i][Ib'=0..63] for I in [p*64,(p+1)*64)
  f32x4 o[2][2];
#pragma unroll
  for (int tr = 0; tr < 2; ++tr)
#pragma unroll
    for (int tm = 0; tm < 2; ++tm) o[tr][tm] = {0.f, 0.f, 0.f, 0.f};
#pragma unroll
  for (int p = 0; p < 2; ++p) {
    if (p) __syncthreads();            // phase-0 reads complete before overwrite
    if (wr == p) {
#pragma unroll
      for (int ti = 0; ti < 4; ++ti)
#pragma unroll
        for (int tj = 0; tj < 4; ++tj) {
          int i = wc * 64 + tj * 16 + lr;
          int Ib = ti * 16 + kq * 4;
          uint2 pk;
          pk.x = pk2(e[ti][tj][0], e[ti][tj][1]);
          pk.y = pk2(e[ti][tj][2], e[ti][tj][3]);
          *(uint2*)&lds[WtO + i * 72 + Ib] = pk;
        }
    }
    __syncthreads();
#pragma unroll
    for (int ks = 0; ks < 2; ++ks) {
      short8 ea[2], vf[2];
#pragma unroll
      for (int tr = 0; tr < 2; ++tr)
        ea[tr] = *(const short8*)&lds[WtO + (wv * 32 + tr * 16 + lr) * 72 + ks * 32 + kq * 8];
#pragma unroll
      for (int tm = 0; tm < 2; ++tm)
        vf[tm] = *(const short8*)&lds[VtO + (tm * 16 + lr) * 136 + p * 64 + ks * 32 + kq * 8];
#pragma unroll
      for (int tr = 0; tr < 2; ++tr)
#pragma unroll
        for (int tm = 0; tm < 2; ++tm)
          o[tr][tm] = __builtin_amdgcn_mfma_f32_16x16x32_bf16(ea[tr], vf[tm], o[tr][tm], 0, 0, 0);
    }
  }
#pragma unroll
  for (int tr = 0; tr < 2; ++tr)
#pragma unroll
    for (int tm = 0; tm < 2; ++tm)
#pragma unroll
      for (int r = 0; r < 4; ++r) {
        int row = wv * 32 + tr * 16 + kq * 4 + r;
        lds[row * 40 + tm * 16 + lr] = (short)f2bf(o[tr][tm][r]);
      }
  __syncthreads();
#pragma unroll
  for (int u = 0; u < 2; ++u) {
    int idx = t + u * 256;
    int i = idx >> 2, mg = idx & 3;
    uint4 vv = *(const uint4*)&lds[i * 40 + mg * 8];
    *(uint4*)(At + ((size_t)(i * Pp + j0 + jj) * OUTC + h * 32 + mg * 8)) = vv;
  }
}

// ---------------------------------------------------------------------------
// Point attention, MFMA. r8: Q fragments direct global->VGPR (no Q LDS),
// LDS 36864 B -> 4 blocks/CU; J-half-split PV (r7); swizzled K staging.
__global__ __launch_bounds__(256, 4) void point_attn_mfma(const short* __restrict__ P,
                                                          short* __restrict__ PA,
                                                          int icShift) {
  constexpr int KsO = 0, VtO = 4096, EO = 8448, CsO = 17664;
  __shared__ __align__(16) short lds[18432];
  float* cs    = (float*)&lds[CsO];
  float* denom = cs + 256;
  const int IC = 1 << icShift;
  const int bx = blockIdx.x;
  const int h    = bx >> (icShift + 1);
  const int rem  = bx & ((IC << 1) - 1);
  const int ii   = rem >> 1;
  const int half = rem & 1;
  const int t  = threadIdx.x;
  const int wv = t >> 6, ln = t & 63;
  const int wr = wv >> 1, wc = wv & 1;
  const int lr = ln & 15, kq = ln >> 4;
  const size_t WC = (size_t)(Hh << icShift) * 8192;
  const short* qb = P + (size_t)(h * IC + ii) * 8192 + half * 4096;
  const short* kb = P + WC + (size_t)(h * IC + ii) * 8192;
  const short* vb = kb + WC;

  const int lnoff = (ln >> 2) * 32 + (((ln & 3) ^ ((ln >> 3) & 3)) * 8);
  const int qkslot = (kq ^ ((lr >> 1) & 3)) * 8;

  // Q fragments direct from global (row-major 128x32, 16B-aligned rows).
  short8 bf[4];
#pragma unroll
  for (int tj = 0; tj < 4; ++tj)
    bf[tj] = *(const short8*)(qb + (wc * 64 + tj * 16 + lr) * 32 + kq * 8);

  f32x4 o[2][2];
#pragma unroll
  for (int tr = 0; tr < 2; ++tr)
#pragma unroll
    for (int tm = 0; tm < 2; ++tm) o[tr][tm] = {0.f, 0.f, 0.f, 0.f};

  for (int chunk = 0; chunk < 2; ++chunk) {
    const int Jb = chunk * 128;
    if (chunk) __syncthreads();
#pragma unroll
    for (int u = 0; u < 2; ++u) {
      int seg = wv * 2 + u;
      __builtin_amdgcn_global_load_lds(
          (const __attribute__((address_space(1))) void*)(kb + Jb * 32 + seg * 512 + lnoff),
          (__attribute__((address_space(3))) void*)&lds[KsO + seg * 512], 16, 0, 0);
    }
    if (chunk == 0) {
      if (t < 128) denom[t] = 0.f;
    }
#pragma unroll
    for (int u = 0; u < 2; ++u) {
      int idx = t + u * 256;
      int Jl = idx >> 2, g = idx & 3;
      uint4 v = *(const uint4*)(vb + Jb * 32 + idx * 8);
      unsigned w0 = v.x, w1 = v.y, w2 = v.z, w3 = v.w;
      if (g & 1) { unsigned tp = w0; w0 = w1; w1 = w2; w2 = w3; w3 = tp; }
      if (g & 2) { unsigned t0 = w0, t1 = w1; w0 = w2; w1 = w3; w2 = t0; w3 = t1; }
      const unsigned wa[4] = {w0, w1, w2, w3};
      int m0 = g * 8, g2 = g * 2;
#pragma unroll
      for (int k = 0; k < 4; ++k) {
        int q = (2 * k + g2) & 7;
        lds[VtO + (m0 + q) * 136 + Jl]     = (short)(wa[k] & 0xffffu);
        lds[VtO + (m0 + q + 1) * 136 + Jl] = (short)(wa[k] >> 16);
      }
    }
    __syncthreads();

    short8 af[4];
#pragma unroll
    for (int ti = 0; ti < 4; ++ti)
      af[ti] = *(const short8*)&lds[KsO + (wr * 64 + ti * 16 + lr) * 32 + qkslot];
    f32x4 e[4][4];
#pragma unroll
    for (int ti = 0; ti < 4; ++ti)
#pragma unroll
      for (int tj = 0; tj < 4; ++tj) e[ti][tj] = {0.f, 0.f, 0.f, 0.f};
#pragma unroll
    for (int ti = 0; ti < 4; ++ti)
#pragma unroll
      for (int tj = 0; tj < 4; ++tj)
        e[ti][tj] = __builtin_amdgcn_mfma_f32_16x16x32_bf16(af[ti], bf[tj], e[ti][tj], 0, 0, 0);

    float cp[4] = {0.f, 0.f, 0.f, 0.f};
#pragma unroll
    for (int ti = 0; ti < 4; ++ti)
#pragma unroll
      for (int tj = 0; tj < 4; ++tj)
#pragma unroll
        for (int r = 0; r < 4; ++r) {
          float ex = __expf(e[ti][tj][r]);
          e[ti][tj][r] = ex;
          cp[tj] += ex;
        }
#pragma unroll
    for (int tj = 0; tj < 4; ++tj) {
      cp[tj] += __shfl_xor(cp[tj], 16, 64);
      cp[tj] += __shfl_xor(cp[tj], 32, 64);
    }
    if (kq == 0) {
#pragma unroll
      for (int tj = 0; tj < 4; ++tj)
        cs[wr * 128 + wc * 64 + tj * 16 + lr] = cp[tj];
    }

    // J-half-split PV: phase p stores E rows [j][Jl'=0..63] for Jl in
    // [p*64,(p+1)*64) (written by waves with wr==p), then PV with K=64.
#pragma unroll
    for (int p = 0; p < 2; ++p) {
      if (p) __syncthreads();          // phase-0 reads complete before overwrite
      if (wr == p) {
#pragma unroll
        for (int ti = 0; ti < 4; ++ti)
#pragma unroll
          for (int tj = 0; tj < 4; ++tj) {
            int j  = wc * 64 + tj * 16 + lr;
            int Jl = ti * 16 + kq * 4;
            uint2 pk;
            pk.x = pk2(e[ti][tj][0], e[ti][tj][1]);
            pk.y = pk2(e[ti][tj][2], e[ti][tj][3]);
            *(uint2*)&lds[EO + j * 72 + Jl] = pk;
          }
      }
      __syncthreads();
      if (p == 0 && t < 128) denom[t] += cs[t] + cs[128 + t];
#pragma unroll
      for (int ks = 0; ks < 2; ++ks) {
        short8 ea[2], vf[2];
#pragma unroll
        for (int tr = 0; tr < 2; ++tr)
          ea[tr] = *(const short8*)&lds[EO + (wv * 32 + tr * 16 + lr) * 72 + ks * 32 + kq * 8];
#pragma unroll
        for (int tm = 0; tm < 2; ++tm)
          vf[tm] = *(const short8*)&lds[VtO + (tm * 16 + lr) * 136 + p * 64 + ks * 32 + kq * 8];
#pragma unroll
        for (int tr = 0; tr < 2; ++tr)
#pragma unroll
          for (int tm = 0; tm < 2; ++tm)
            o[tr][tm] = __builtin_amdgcn_mfma_f32_16x16x32_bf16(ea[tr], vf[tm], o[tr][tm], 0, 0, 0);
      }
    }
  }
  __syncthreads();

#pragma unroll
  for (int tr = 0; tr < 2; ++tr)
#pragma unroll
    for (int r = 0; r < 4; ++r) {
      int row = wv * 32 + tr * 16 + kq * 4 + r;
      float rinv = 1.f / denom[row];
#pragma unroll
      for (int tm = 0; tm < 2; ++tm)
        lds[row * 40 + tm * 16 + lr] = (short)f2bf(o[tr][tm][r] * rinv);
    }
  __syncthreads();
#pragma unroll
  for (int u = 0; u < 2; ++u) {
    int idx = t + u * 256;
    int jl = idx >> 2, mg = idx & 3;
    uint4 vv = *(const uint4*)&lds[jl * 40 + mg * 8];
    *(uint4*)(PA + ((size_t)(ii * Pp + half * 128 + jl) * OUTC + h * 32 + mg * 8)) = vv;
  }
}

// ---------------------------------------------------------------------------
extern "C" void kernel_launch(void* const* d_in, const int* in_sizes, int n_in,
                              void* d_out, int out_size, void* d_ws, size_t ws_size,
                              hipStream_t stream) {
  const float* x  = (const float*)d_in[0];
  const float* Wt = (const float*)d_in[1];
  const float* Wp = (const float*)d_in[2];
  const float* W1 = (const float*)d_in[3];
  const float* b1 = (const float*)d_in[4];
  const float* W2 = (const float*)d_in[5];
  const float* b2 = (const float*)d_in[6];
  float* out = (float*)d_out;
  short* ws  = (short*)d_ws;

  const size_t fixedH = 8388608 + 16777216 + 393216 + 786432 + 1048576 + 1048576
                      + 262144 + 1024 + 4194304 + 65536;
  size_t availH = ws_size / 2;
  size_t chF; int JC, IC;
  if      (availH >= fixedH + 50331648) { chF = 50331648; JC = 256; IC = 128; }
  else if (availH >= fixedH + 12582912) { chF = 12582912; JC = 64;  IC = 32;  }
  else if (availH >= fixedH + 6291456)  { chF = 6291456;  JC = 32;  IC = 16;  }
  else                                  { chF = 3145728;  JC = 16;  IC = 8;   }
  short* CH  = ws;
  short* xbf = CH + chF;
  short* At  = xbf + 8388608;
  short* B1t = At + 16777216;
  short* B2t = B1t + 393216;
  short* W1b = B2t + 786432;      // W1 as bf16 row-major (512 x 2048)
  short* W2t = W1b + 1048576;     // W2^T bf16 (512 x 2048)
  short* Wct = W2t + 1048576;     // (W1@W2)^T bf16 (512 x 512): Wct[o][k]
  float* bcF   = (float*)(Wct + 262144);                   // 512 fp32
  float* partF = (float*)(Wct + 262144 + 1024);            // 8 x 512 x 512 fp32
  float* bcP   = (float*)(Wct + 262144 + 1024 + 4194304);  // 64 x 512 fp32
  const int jcS = __builtin_ctz((unsigned)JC);
  const int icS = __builtin_ctz((unsigned)IC);

  conv_x<<<4096, 256, 0, stream>>>(x, xbf);
  conv_x<<<512, 256, 0, stream>>>(W1, W1b);
  transpose_to_bf16<<<dim3(8, 4, 3), 256, 0, stream>>>(Wt, B1t, 256, 512);
  repack_b2t<<<3072, 256, 0, stream>>>(Wp, B2t);
  transpose_to_bf16<<<dim3(8, 32, 1), 256, 0, stream>>>(W2, W2t, 2048, 512);

  // MLP is linear (no activation): fold W1@W2 -> Wc, b1@W2+b2 -> bc.
  wc_splitk<<<dim3(4, 4, 8), 256, 0, stream>>>(W2t, W1b, partF);
  wc_reduce<<<1024, 256, 0, stream>>>(partF, Wct);
  bc_partial<<<64, 256, 0, stream>>>(b1, W2, bcP);
  bc_finish<<<2, 256, 0, stream>>>(bcP, b2, bcF);

  if (JC == 256) {
    // Temporal QKV: retiled (AMAP=3) -> contiguous staged writes (EPI=3).
    gemm_mfma<256, 1536, 3, 3, 0><<<dim3(12, 256), 256, 0, stream>>>(xbf, B1t, CH, nullptr, 0, 0, 256);
    temporal_attn_mfma<<<Hh * 256, 256, 0, stream>>>(CH, At, 0, 8);
    gemm_mfma<512, 1536, 0, 2, 0><<<dim3(12, 256), 256, 0, stream>>>(At, B2t, CH, nullptr, 0, 0, 128);
    point_attn_mfma<<<Hh * 128 * 2, 256, 0, stream>>>(CH, At, 7);
  } else {
    for (int j0 = 0; j0 < Pp; j0 += JC) {
      gemm_mfma<256, 1536, 1, 1, 0><<<dim3(12, JC), 256, 0, stream>>>(xbf, B1t, CH, nullptr, j0, jcS, JC);
      temporal_attn_mfma<<<Hh * JC, 256, 0, stream>>>(CH, At, j0, jcS);
    }
    for (int i0 = 0; i0 < Nf; i0 += IC) {
      short* Arows = At + (size_t)i0 * Pp * OUTC;
      gemm_mfma<512, 1536, 0, 2, 0><<<dim3(12, IC * 2), 256, 0, stream>>>(Arows, B2t, CH, nullptr, 0, 0, IC);
      point_attn_mfma<<<Hh * IC * 2, 256, 0, stream>>>(CH, Arows, icS);
    }
  }

  // Single fused-MLP GEMM: out = At @ Wct^T + bc  (32768 x 512, K = 512)
  gemm_mfma<512, 512, 0, 0, 1><<<dim3(4, 256), 256, 0, stream>>>(At, Wct, out, bcF, 0, 0, 0);
}

// Round 9
// 370.190 us; speedup vs baseline: 1.0004x; 1.0004x over previous
//
#include <hip/hip_runtime.h>
#include <cstddef>
#include <cstdint>

constexpr int Nf = 128, Pp = 256, Dd = 256, Hh = 16, Mm = 32;
constexpr int OUTC = 512, HID = 2048, C3 = 1536;

typedef short short8 __attribute__((ext_vector_type(8)));   // 8 bf16 (4 VGPRs)
typedef float f32x4 __attribute__((ext_vector_type(4)));    // 4 fp32 acc

// fp32 -> bf16 round-to-nearest-even (scalar sites)
__device__ inline unsigned short f2bf(float f) {
  unsigned u = __float_as_uint(f);
  u += 0x7fffu + ((u >> 16) & 1u);
  return (unsigned short)(u >> 16);
}
// packed pair via HW cvt (RNE), 1 op per 2 values (T12 recipe)
__device__ inline unsigned pk2(float a, float b) {
  unsigned r;
  asm("v_cvt_pk_bf16_f32 %0, %1, %2" : "=v"(r) : "v"(a), "v"(b));
  return r;
}

// ---------------------------------------------------------------------------
__global__ __launch_bounds__(256) void conv_x(const float* __restrict__ x,
                                              short* __restrict__ xb) {
  int idx = blockIdx.x * 256 + threadIdx.x;
  const float4* s = (const float4*)x + (size_t)idx * 2;
  float4 a = s[0], c = s[1];
  uint4 o;
  o.x = pk2(a.x, a.y); o.y = pk2(a.z, a.w);
  o.z = pk2(c.x, c.y); o.w = pk2(c.z, c.w);
  ((uint4*)xb)[idx] = o;
}

// Generic coalesced transpose: in (R x C fp32, slice z) -> out (C x R bf16).
__global__ __launch_bounds__(256) void transpose_to_bf16(const float* __restrict__ in,
                                                         short* __restrict__ out,
                                                         int R, int C) {
  __shared__ float tile[64 * 65];
  const int t = threadIdx.x;
  const int rb = blockIdx.y * 64, cb = blockIdx.x * 64;
  const size_t sl = (size_t)blockIdx.z * R * C;
#pragma unroll
  for (int u = 0; u < 4; ++u) {
    int r = (t >> 4) + u * 16, c4 = (t & 15) * 4;
    float4 v = *(const float4*)(in + sl + (size_t)(rb + r) * C + cb + c4);
    tile[r * 65 + c4 + 0] = v.x;
    tile[r * 65 + c4 + 1] = v.y;
    tile[r * 65 + c4 + 2] = v.z;
    tile[r * 65 + c4 + 3] = v.w;
  }
  __syncthreads();
#pragma unroll
  for (int u = 0; u < 2; ++u) {
    int id = t + u * 256;
    int n = id >> 3, kg = id & 7;
    float a[8];
#pragma unroll
    for (int q = 0; q < 8; ++q) a[q] = tile[(kg * 8 + q) * 65 + n];
    uint4 o;
    o.x = pk2(a[0], a[1]); o.y = pk2(a[2], a[3]);
    o.z = pk2(a[4], a[5]); o.w = pk2(a[6], a[7]);
    *(uint4*)(out + sl + (size_t)(cb + n) * R + rb + kg * 8) = o;
  }
}

// B2t[c][k], k = HH*32+MM (1536 x 512)
__global__ void repack_b2t(const float* __restrict__ Wp, short* __restrict__ B2t) {
  int idx = blockIdx.x * 256 + threadIdx.x;  // 786432
  int c = idx >> 9, k = idx & 511;
  int w = c >> 9, h = (c >> 5) & 15, m = c & 31;
  int HH = k >> 5, MM = k & 31;
  B2t[idx] = (short)f2bf(Wp[(((w * Hh + h) * Mm + m) * Hh + HH) * Mm + MM]);
}

// ---------------------------------------------------------------------------
// MLP collapse helpers (run once; small).
__global__ __launch_bounds__(256) void wc_splitk(const short* __restrict__ A,   // W2t: 512 x 2048
                                                 const short* __restrict__ Bt,  // W1 bf16: 512 x 2048
                                                 float* __restrict__ part) {
  __shared__ short As[128 * 32];
  __shared__ short Bs[128 * 32];
  const int t = threadIdx.x;
  const int wv = t >> 6, ln = t & 63;
  const int wr = wv >> 1, wc = wv & 1;
  const int lr = ln & 15, kq = ln >> 4;
  const int row0 = blockIdx.y * 128, col0 = blockIdx.x * 128;
  const int k0 = blockIdx.z * 256;

  f32x4 acc[4][4];
#pragma unroll
  for (int i = 0; i < 4; ++i)
#pragma unroll
    for (int j = 0; j < 4; ++j) acc[i][j] = {0.f, 0.f, 0.f, 0.f};

  for (int kt = k0; kt < k0 + 256; kt += 32) {
#pragma unroll
    for (int u = 0; u < 2; ++u) {
      int seg = wv * 128 + u * 64 + ln;
      int r = seg >> 2, kg = seg & 3;
      const short* gp = A + (size_t)(row0 + r) * HID + kt + kg * 8;
      __builtin_amdgcn_global_load_lds(
          (const __attribute__((address_space(1))) void*)gp,
          (__attribute__((address_space(3))) void*)&As[(wv * 128 + u * 64) * 8], 16, 0, 0);
    }
#pragma unroll
    for (int u = 0; u < 2; ++u) {
      int seg = wv * 128 + u * 64 + ln;
      int r = seg >> 2, kg = seg & 3;
      const short* gp = Bt + (size_t)(col0 + r) * HID + kt + kg * 8;
      __builtin_amdgcn_global_load_lds(
          (const __attribute__((address_space(1))) void*)gp,
          (__attribute__((address_space(3))) void*)&Bs[(wv * 128 + u * 64) * 8], 16, 0, 0);
    }
    __syncthreads();
    short8 a[4], b[4];
#pragma unroll
    for (int ti = 0; ti < 4; ++ti)
      a[ti] = *(const short8*)&As[(wr * 64 + ti * 16 + lr) * 32 + kq * 8];
#pragma unroll
    for (int tj = 0; tj < 4; ++tj)
      b[tj] = *(const short8*)&Bs[(wc * 64 + tj * 16 + lr) * 32 + kq * 8];
#pragma unroll
    for (int ti = 0; ti < 4; ++ti)
#pragma unroll
      for (int tj = 0; tj < 4; ++tj)
        acc[ti][tj] = __builtin_amdgcn_mfma_f32_16x16x32_bf16(a[ti], b[tj], acc[ti][tj], 0, 0, 0);
    __syncthreads();
  }

#pragma unroll
  for (int tj = 0; tj < 4; ++tj) {
    int gcol = col0 + wc * 64 + tj * 16 + lr;
#pragma unroll
    for (int ti = 0; ti < 4; ++ti)
#pragma unroll
      for (int rg = 0; rg < 4; ++rg) {
        int grow = row0 + wr * 64 + ti * 16 + kq * 4 + rg;
        part[((size_t)blockIdx.z * 512 + grow) * 512 + gcol] = acc[ti][tj][rg];
      }
  }
}

__global__ __launch_bounds__(256) void wc_reduce(const float* __restrict__ part,
                                                 short* __restrict__ Wct) {
  int idx = blockIdx.x * 256 + threadIdx.x;  // 262144
  float s = 0.f;
#pragma unroll
  for (int z = 0; z < 8; ++z) s += part[(size_t)z * 262144 + idx];
  Wct[idx] = (short)f2bf(s);
}

__global__ __launch_bounds__(256) void bc_partial(const float* __restrict__ b1,
                                                  const float* __restrict__ W2,
                                                  float* __restrict__ part) {
  const int z = blockIdx.x;       // 64 chunks of 32 h
  const int t = threadIdx.x;
  float s0 = 0.f, s1 = 0.f;
#pragma unroll
  for (int hh = 0; hh < 32; ++hh) {
    int h = z * 32 + hh;
    float bv = b1[h];
    s0 += bv * W2[(size_t)h * OUTC + t];
    s1 += bv * W2[(size_t)h * OUTC + t + 256];
  }
  part[z * OUTC + t] = s0;
  part[z * OUTC + t + 256] = s1;
}

__global__ __launch_bounds__(256) void bc_finish(const float* __restrict__ part,
                                                 const float* __restrict__ b2,
                                                 float* __restrict__ bc) {
  int o = blockIdx.x * 256 + threadIdx.x;  // 512
  float s = b2[o];
#pragma unroll
  for (int z = 0; z < 64; ++z) s += part[z * OUTC + o];
  bc[o] = s;
}

// ---------------------------------------------------------------------------
// bf16 MFMA GEMM, counted-vmcnt 2-deep pipeline + LDS XOR swizzle (verified r5).
// AMAP: 0 = linear rows; 1 = (i,jj) chunked; 3 = temporal retile;
//       4 = head-major A [k>>5][row][32]     (arow = row)
//       5 = head-major A [k>>5][j][i][32]    (arow = (row&255)*128 + (row>>8))
// Head stride for AMAP 4/5 = 32768*32 = 1048576 shorts.
template <int KDIM, int NCOLS, int AMAP, int EPI, int OUTT>
__global__ __launch_bounds__(256) void gemm_mfma(const short* __restrict__ A,
                                                 const short* __restrict__ Bt,
                                                 void* __restrict__ Cv,
                                                 const float* __restrict__ bias,
                                                 int j0, int pshift, int pc) {
  __shared__ __align__(16) short SH[16384];   // As[2] | Bs[2]; reused as outb
  const int t = threadIdx.x;
  const int wv = t >> 6, ln = t & 63;
  const int wr = wv >> 1, wc = wv & 1;
  const int lr = ln & 15, kq = ln >> 4;

  constexpr int NBX = NCOLS / 128;
  constexpr int NT = KDIM / 32;
  int lin = blockIdx.y * NBX + blockIdx.x;
  int nblk = gridDim.x * gridDim.y;
  int bx, by;
  if ((nblk & 7) == 0) {
    int per = nblk >> 3;
    int id = (lin & 7) * per + (lin >> 3);   // bijective; groups rows per XCD
    bx = id % NBX; by = id / NBX;
  } else {
    bx = blockIdx.x; by = blockIdx.y;
  }
  const int row0 = by * 128, col0 = bx * 128;

  // Staging geometry (constant per thread).
  const int seg0 = wv * 128 + ln;
  const int seg1 = wv * 128 + 64 + ln;
  const int r0 = seg0 >> 2, r1 = seg1 >> 2;
  const int kg0 = (seg0 & 3) ^ ((r0 >> 1) & 3);   // pre-swizzled source chunk
  const int kg1 = (seg1 & 3) ^ ((r1 >> 1) & 3);
  size_t aoff0, aoff1;   // kt-independent part of the A offset
  {
    int rr = row0 + r0;
    if (AMAP == 0)      aoff0 = (size_t)rr * KDIM;
    else if (AMAP == 3) aoff0 = (size_t)(((rr & 127) << 8) + (rr >> 7)) * KDIM;
    else if (AMAP == 4) aoff0 = (size_t)rr * 32;
    else if (AMAP == 5) aoff0 = (size_t)(((rr & 255) << 7) + (rr >> 8)) * 32;
    else { int i = rr >> pshift, jj = rr & (pc - 1); aoff0 = (size_t)((i << 8) + j0 + jj) * KDIM; }
    rr = row0 + r1;
    if (AMAP == 0)      aoff1 = (size_t)rr * KDIM;
    else if (AMAP == 3) aoff1 = (size_t)(((rr & 127) << 8) + (rr >> 7)) * KDIM;
    else if (AMAP == 4) aoff1 = (size_t)rr * 32;
    else if (AMAP == 5) aoff1 = (size_t)(((rr & 255) << 7) + (rr >> 8)) * 32;
    else { int i = rr >> pshift, jj = rr & (pc - 1); aoff1 = (size_t)((i << 8) + j0 + jj) * KDIM; }
  }
  const size_t brow0 = (size_t)(col0 + r0), brow1 = (size_t)(col0 + r1);

  auto stage = [&](int buf, int tk) {
    const int kt = tk * 32;
    const size_t kb = (AMAP >= 4) ? (size_t)tk * 1048576 : (size_t)kt;
    __builtin_amdgcn_global_load_lds(
        (const __attribute__((address_space(1))) void*)(A + aoff0 + kb + kg0 * 8),
        (__attribute__((address_space(3))) void*)&SH[buf * 4096 + (wv * 128) * 8], 16, 0, 0);
    __builtin_amdgcn_global_load_lds(
        (const __attribute__((address_space(1))) void*)(A + aoff1 + kb + kg1 * 8),
        (__attribute__((address_space(3))) void*)&SH[buf * 4096 + (wv * 128 + 64) * 8], 16, 0, 0);
    __builtin_amdgcn_global_load_lds(
        (const __attribute__((address_space(1))) void*)(Bt + brow0 * KDIM + kt + kg0 * 8),
        (__attribute__((address_space(3))) void*)&SH[8192 + buf * 4096 + (wv * 128) * 8], 16, 0, 0);
    __builtin_amdgcn_global_load_lds(
        (const __attribute__((address_space(1))) void*)(Bt + brow1 * KDIM + kt + kg1 * 8),
        (__attribute__((address_space(3))) void*)&SH[8192 + buf * 4096 + (wv * 128 + 64) * 8], 16, 0, 0);
  };

  f32x4 acc[4][4];
#pragma unroll
  for (int i = 0; i < 4; ++i)
#pragma unroll
    for (int j = 0; j < 4; ++j) acc[i][j] = {0.f, 0.f, 0.f, 0.f};

  const int slot = kq ^ ((lr >> 1) & 3);   // swizzled fragment slot

  stage(0, 0);
  stage(1, 1);
  asm volatile("s_waitcnt vmcnt(4)" ::: "memory");
  __builtin_amdgcn_s_barrier();

  for (int tk = 0; tk < NT; ++tk) {
    const int cur = tk & 1;
    short8 a[4], b[4];
#pragma unroll
    for (int ti = 0; ti < 4; ++ti)
      a[ti] = *(const short8*)&SH[cur * 4096 + (wr * 64 + ti * 16 + lr) * 32 + slot * 8];
#pragma unroll
    for (int tj = 0; tj < 4; ++tj)
      b[tj] = *(const short8*)&SH[8192 + cur * 4096 + (wc * 64 + tj * 16 + lr) * 32 + slot * 8];
    __builtin_amdgcn_sched_barrier(0);
    asm volatile("s_waitcnt lgkmcnt(0)" ::: "memory");
    __builtin_amdgcn_sched_barrier(0);
    if (tk + 1 < NT) {
      __builtin_amdgcn_s_barrier();        // all waves done reading buf[cur]
      if (tk + 2 < NT) stage(cur, tk + 2);
    }
#pragma unroll
    for (int ti = 0; ti < 4; ++ti)
#pragma unroll
      for (int tj = 0; tj < 4; ++tj)
        acc[ti][tj] = __builtin_amdgcn_mfma_f32_16x16x32_bf16(a[ti], b[tj], acc[ti][tj], 0, 0, 0);
    if (tk + 1 < NT) {
      if (tk + 2 < NT) {
        asm volatile("s_waitcnt vmcnt(4)" ::: "memory");
      } else {
        asm volatile("s_waitcnt vmcnt(0)" ::: "memory");
      }
      __builtin_amdgcn_s_barrier();
      __builtin_amdgcn_sched_barrier(0);
    }
  }

  if (EPI == 0 || EPI == 1) {
#pragma unroll
    for (int tj = 0; tj < 4; ++tj) {
      int gcol = col0 + wc * 64 + tj * 16 + lr;
      float bv = (EPI == 0) ? bias[gcol] : 0.f;
#pragma unroll
      for (int ti = 0; ti < 4; ++ti) {
#pragma unroll
        for (int rg = 0; rg < 4; ++rg) {
          int grow = row0 + wr * 64 + ti * 16 + kq * 4 + rg;
          float val = acc[ti][tj][rg];
          if (EPI == 0) {
            val += bv;
            if (OUTT == 0) ((short*)Cv)[(size_t)grow * NCOLS + gcol] = (short)f2bf(val);
            else           ((float*)Cv)[(size_t)grow * NCOLS + gcol] = val;
          } else {
            int w = gcol >> 9, h = (gcol >> 5) & 15, m = gcol & 31;
            int i = grow >> pshift, jj = grow & (pc - 1);
            size_t addr = (((size_t)(w * Hh + h) * pc + jj) * Nf + i) * Mm + m;
            ((short*)Cv)[addr] = (short)f2bf(val);
          }
        }
      }
    }
  } else {
    // LDS-staged coalesced epilogue (EPI==2 point layout, EPI==3 temporal).
    __builtin_amdgcn_s_barrier();   // all waves done with SH (reads complete)
#pragma unroll
    for (int ti = 0; ti < 4; ++ti)
#pragma unroll
      for (int tj = 0; tj < 4; ++tj) {
        int c = wc * 64 + tj * 16 + lr;
        int q = c >> 5, m = c & 31;
#pragma unroll
        for (int rg = 0; rg < 4; ++rg) {
          int g = wr * 64 + ti * 16 + kq * 4 + rg;
          SH[q * 4096 + g * 32 + (m ^ ((g & 4) << 2))] = (short)f2bf(acc[ti][tj][rg]);
        }
      }
    __syncthreads();
#pragma unroll
    for (int u = 0; u < 8; ++u) {
      int id = u * 256 + t;
      int q = id >> 9, rem = id & 511, g = rem >> 2, mc = (rem & 3) * 8;
      uint4 v = *(const uint4*)&SH[q * 4096 + g * 32 + (mc ^ ((g & 4) << 2))];
      int gc = col0 + q * 32;
      int w = gc >> 9, h = (gc >> 5) & 15;
      size_t base;
      if (EPI == 3) base = ((size_t)(w * Hh + h) * 256 + (row0 >> 7)) * 4096;
      else          base = (((size_t)(w * Hh + h) * pc + (row0 >> 8)) * 256 + (row0 & 255)) * 32;
      *(uint4*)((short*)Cv + base + g * 32 + mc) = v;
    }
  }
}

// ---------------------------------------------------------------------------
// Temporal attention, MFMA. r9: LAYOUT=1 writes head-major T_out[h][jj][i][m]
// (contiguous 8KB per block); LAYOUT=0 = legacy row-major At (fallback).
template <int LAYOUT>
__global__ __launch_bounds__(256, 4) void temporal_attn_mfma(const short* __restrict__ T,
                                                             short* __restrict__ At,
                                                             int j0, int jcShift) {
  constexpr int KsO = 0, VtO = 4096, WtO = 8448, RsO = 17664;
  __shared__ __align__(16) short lds[18176];
  float* rs = (float*)&lds[RsO];
  const int JC = 1 << jcShift;
  const int h  = blockIdx.x >> jcShift;
  const int jj = blockIdx.x & (JC - 1);
  const int t  = threadIdx.x;
  const int wv = t >> 6, ln = t & 63;
  const int wr = wv >> 1, wc = wv & 1;
  const int lr = ln & 15, kq = ln >> 4;
  const size_t WC = (size_t)(Hh << jcShift) * 4096;
  const short* qb = T + (size_t)(h * JC + jj) * 4096;
  const short* kb = qb + WC;
  const short* vb = qb + 2 * WC;

  const int lnoff = (ln >> 2) * 32 + (((ln & 3) ^ ((ln >> 3) & 3)) * 8);
  const int qkslot = (kq ^ ((lr >> 1) & 3)) * 8;   // swizzled fragment slot

  // Q fragments direct from global (row-major 128x32, 16B-aligned rows).
  short8 af[4];
#pragma unroll
  for (int ti = 0; ti < 4; ++ti)
    af[ti] = *(const short8*)(qb + (wr * 64 + ti * 16 + lr) * 32 + kq * 8);

#pragma unroll
  for (int u = 0; u < 2; ++u) {
    int seg = wv * 2 + u;
    __builtin_amdgcn_global_load_lds(
        (const __attribute__((address_space(1))) void*)(kb + seg * 512 + lnoff),
        (__attribute__((address_space(3))) void*)&lds[KsO + seg * 512], 16, 0, 0);
  }
#pragma unroll
  for (int u = 0; u < 2; ++u) {
    int idx = t + u * 256;
    int I = idx >> 2, g = idx & 3;
    uint4 v = *(const uint4*)(vb + idx * 8);
    unsigned w0 = v.x, w1 = v.y, w2 = v.z, w3 = v.w;
    if (g & 1) { unsigned tp = w0; w0 = w1; w1 = w2; w2 = w3; w3 = tp; }
    if (g & 2) { unsigned t0 = w0, t1 = w1; w0 = w2; w1 = w3; w2 = t0; w3 = t1; }
    const unsigned wa[4] = {w0, w1, w2, w3};
    int m0 = g * 8, g2 = g * 2;
#pragma unroll
    for (int k = 0; k < 4; ++k) {
      int q = (2 * k + g2) & 7;
      lds[VtO + (m0 + q) * 136 + I]     = (short)(wa[k] & 0xffffu);
      lds[VtO + (m0 + q + 1) * 136 + I] = (short)(wa[k] >> 16);
    }
  }
  __syncthreads();

  short8 bf[4];
#pragma unroll
  for (int tj = 0; tj < 4; ++tj)
    bf[tj] = *(const short8*)&lds[KsO + (wc * 64 + tj * 16 + lr) * 32 + qkslot];
  f32x4 e[4][4];
#pragma unroll
  for (int ti = 0; ti < 4; ++ti)
#pragma unroll
    for (int tj = 0; tj < 4; ++tj) e[ti][tj] = {0.f, 0.f, 0.f, 0.f};
#pragma unroll
  for (int ti = 0; ti < 4; ++ti)
#pragma unroll
    for (int tj = 0; tj < 4; ++tj)
      e[ti][tj] = __builtin_amdgcn_mfma_f32_16x16x32_bf16(af[ti], bf[tj], e[ti][tj], 0, 0, 0);

  float part[4][4];
#pragma unroll
  for (int ti = 0; ti < 4; ++ti)
#pragma unroll
    for (int r = 0; r < 4; ++r) {
      float p = 0.f;
#pragma unroll
      for (int tj = 0; tj < 4; ++tj) {
        float ex = __expf(e[ti][tj][r]);
        e[ti][tj][r] = ex;
        p += ex;
      }
      part[ti][r] = p;
    }
#pragma unroll
  for (int msk = 1; msk <= 8; msk <<= 1)
#pragma unroll
    for (int ti = 0; ti < 4; ++ti)
#pragma unroll
      for (int r = 0; r < 4; ++r)
        part[ti][r] += __shfl_xor(part[ti][r], msk, 64);
  if (lr == 0) {
#pragma unroll
    for (int ti = 0; ti < 4; ++ti)
#pragma unroll
      for (int r = 0; r < 4; ++r)
        rs[wc * 128 + wr * 64 + ti * 16 + kq * 4 + r] = part[ti][r];
  }
  __syncthreads();

  // normalize all P in registers
#pragma unroll
  for (int ti = 0; ti < 4; ++ti)
#pragma unroll
    for (int r = 0; r < 4; ++r) {
      int I = wr * 64 + ti * 16 + kq * 4 + r;
      float inv = 1.f / (rs[I] + rs[128 + I]);
#pragma unroll
      for (int tj = 0; tj < 4; ++tj) e[ti][tj][r] *= inv;
    }

  // J-half-split PV: phase p uses Wt rows [i][Ib'=0..63] for I in [p*64,(p+1)*64)
  f32x4 o[2][2];
#pragma unroll
  for (int tr = 0; tr < 2; ++tr)
#pragma unroll
    for (int tm = 0; tm < 2; ++tm) o[tr][tm] = {0.f, 0.f, 0.f, 0.f};
#pragma unroll
  for (int p = 0; p < 2; ++p) {
    if (p) __syncthreads();            // phase-0 reads complete before overwrite
    if (wr == p) {
#pragma unroll
      for (int ti = 0; ti < 4; ++ti)
#pragma unroll
        for (int tj = 0; tj < 4; ++tj) {
          int i = wc * 64 + tj * 16 + lr;
          int Ib = ti * 16 + kq * 4;
          uint2 pk;
          pk.x = pk2(e[ti][tj][0], e[ti][tj][1]);
          pk.y = pk2(e[ti][tj][2], e[ti][tj][3]);
          *(uint2*)&lds[WtO + i * 72 + Ib] = pk;
        }
    }
    __syncthreads();
#pragma unroll
    for (int ks = 0; ks < 2; ++ks) {
      short8 ea[2], vf[2];
#pragma unroll
      for (int tr = 0; tr < 2; ++tr)
        ea[tr] = *(const short8*)&lds[WtO + (wv * 32 + tr * 16 + lr) * 72 + ks * 32 + kq * 8];
#pragma unroll
      for (int tm = 0; tm < 2; ++tm)
        vf[tm] = *(const short8*)&lds[VtO + (tm * 16 + lr) * 136 + p * 64 + ks * 32 + kq * 8];
#pragma unroll
      for (int tr = 0; tr < 2; ++tr)
#pragma unroll
        for (int tm = 0; tm < 2; ++tm)
          o[tr][tm] = __builtin_amdgcn_mfma_f32_16x16x32_bf16(ea[tr], vf[tm], o[tr][tm], 0, 0, 0);
    }
  }
#pragma unroll
  for (int tr = 0; tr < 2; ++tr)
#pragma unroll
    for (int tm = 0; tm < 2; ++tm)
#pragma unroll
      for (int r = 0; r < 4; ++r) {
        int row = wv * 32 + tr * 16 + kq * 4 + r;
        lds[row * 40 + tm * 16 + lr] = (short)f2bf(o[tr][tm][r]);
      }
  __syncthreads();
  if (LAYOUT == 1) {
    // T_out[h][jj][i][m]: contiguous 8KB per block
    const size_t base = (size_t)(h * 256 + j0 + jj) * 4096;
#pragma unroll
    for (int u = 0; u < 2; ++u) {
      int idx = t + u * 256;
      int i = idx >> 2, mg = idx & 3;
      uint4 vv = *(const uint4*)&lds[i * 40 + mg * 8];
      *(uint4*)(At + base + i * 32 + mg * 8) = vv;
    }
  } else {
#pragma unroll
    for (int u = 0; u < 2; ++u) {
      int idx = t + u * 256;
      int i = idx >> 2, mg = idx & 3;
      uint4 vv = *(const uint4*)&lds[i * 40 + mg * 8];
      *(uint4*)(At + ((size_t)(i * Pp + j0 + jj) * OUTC + h * 32 + mg * 8)) = vv;
    }
  }
}

// ---------------------------------------------------------------------------
// Point attention, MFMA. r9: LAYOUT=1 writes head-major PA[h][i][j][m]
// (contiguous 8KB per block); LAYOUT=0 = legacy row-major At (fallback).
template <int LAYOUT>
__global__ __launch_bounds__(256, 4) void point_attn_mfma(const short* __restrict__ P,
                                                          short* __restrict__ PA,
                                                          int icShift) {
  constexpr int KsO = 0, VtO = 4096, EO = 8448, CsO = 17664;
  __shared__ __align__(16) short lds[18432];
  float* cs    = (float*)&lds[CsO];
  float* denom = cs + 256;
  const int IC = 1 << icShift;
  const int bx = blockIdx.x;
  const int h    = bx >> (icShift + 1);
  const int rem  = bx & ((IC << 1) - 1);
  const int ii   = rem >> 1;
  const int half = rem & 1;
  const int t  = threadIdx.x;
  const int wv = t >> 6, ln = t & 63;
  const int wr = wv >> 1, wc = wv & 1;
  const int lr = ln & 15, kq = ln >> 4;
  const size_t WC = (size_t)(Hh << icShift) * 8192;
  const short* qb = P + (size_t)(h * IC + ii) * 8192 + half * 4096;
  const short* kb = P + WC + (size_t)(h * IC + ii) * 8192;
  const short* vb = kb + WC;

  const int lnoff = (ln >> 2) * 32 + (((ln & 3) ^ ((ln >> 3) & 3)) * 8);
  const int qkslot = (kq ^ ((lr >> 1) & 3)) * 8;

  // Q fragments direct from global (row-major 128x32, 16B-aligned rows).
  short8 bf[4];
#pragma unroll
  for (int tj = 0; tj < 4; ++tj)
    bf[tj] = *(const short8*)(qb + (wc * 64 + tj * 16 + lr) * 32 + kq * 8);

  f32x4 o[2][2];
#pragma unroll
  for (int tr = 0; tr < 2; ++tr)
#pragma unroll
    for (int tm = 0; tm < 2; ++tm) o[tr][tm] = {0.f, 0.f, 0.f, 0.f};

  for (int chunk = 0; chunk < 2; ++chunk) {
    const int Jb = chunk * 128;
    if (chunk) __syncthreads();
#pragma unroll
    for (int u = 0; u < 2; ++u) {
      int seg = wv * 2 + u;
      __builtin_amdgcn_global_load_lds(
          (const __attribute__((address_space(1))) void*)(kb + Jb * 32 + seg * 512 + lnoff),
          (__attribute__((address_space(3))) void*)&lds[KsO + seg * 512], 16, 0, 0);
    }
    if (chunk == 0) {
      if (t < 128) denom[t] = 0.f;
    }
#pragma unroll
    for (int u = 0; u < 2; ++u) {
      int idx = t + u * 256;
      int Jl = idx >> 2, g = idx & 3;
      uint4 v = *(const uint4*)(vb + Jb * 32 + idx * 8);
      unsigned w0 = v.x, w1 = v.y, w2 = v.z, w3 = v.w;
      if (g & 1) { unsigned tp = w0; w0 = w1; w1 = w2; w2 = w3; w3 = tp; }
      if (g & 2) { unsigned t0 = w0, t1 = w1; w0 = w2; w1 = w3; w2 = t0; w3 = t1; }
      const unsigned wa[4] = {w0, w1, w2, w3};
      int m0 = g * 8, g2 = g * 2;
#pragma unroll
      for (int k = 0; k < 4; ++k) {
        int q = (2 * k + g2) & 7;
        lds[VtO + (m0 + q) * 136 + Jl]     = (short)(wa[k] & 0xffffu);
        lds[VtO + (m0 + q + 1) * 136 + Jl] = (short)(wa[k] >> 16);
      }
    }
    __syncthreads();

    short8 af[4];
#pragma unroll
    for (int ti = 0; ti < 4; ++ti)
      af[ti] = *(const short8*)&lds[KsO + (wr * 64 + ti * 16 + lr) * 32 + qkslot];
    f32x4 e[4][4];
#pragma unroll
    for (int ti = 0; ti < 4; ++ti)
#pragma unroll
      for (int tj = 0; tj < 4; ++tj) e[ti][tj] = {0.f, 0.f, 0.f, 0.f};
#pragma unroll
    for (int ti = 0; ti < 4; ++ti)
#pragma unroll
      for (int tj = 0; tj < 4; ++tj)
        e[ti][tj] = __builtin_amdgcn_mfma_f32_16x16x32_bf16(af[ti], bf[tj], e[ti][tj], 0, 0, 0);

    float cp[4] = {0.f, 0.f, 0.f, 0.f};
#pragma unroll
    for (int ti = 0; ti < 4; ++ti)
#pragma unroll
      for (int tj = 0; tj < 4; ++tj)
#pragma unroll
        for (int r = 0; r < 4; ++r) {
          float ex = __expf(e[ti][tj][r]);
          e[ti][tj][r] = ex;
          cp[tj] += ex;
        }
#pragma unroll
    for (int tj = 0; tj < 4; ++tj) {
      cp[tj] += __shfl_xor(cp[tj], 16, 64);
      cp[tj] += __shfl_xor(cp[tj], 32, 64);
    }
    if (kq == 0) {
#pragma unroll
      for (int tj = 0; tj < 4; ++tj)
        cs[wr * 128 + wc * 64 + tj * 16 + lr] = cp[tj];
    }

    // J-half-split PV: phase p stores E rows [j][Jl'=0..63] for Jl in
    // [p*64,(p+1)*64) (written by waves with wr==p), then PV with K=64.
#pragma unroll
    for (int p = 0; p < 2; ++p) {
      if (p) __syncthreads();          // phase-0 reads complete before overwrite
      if (wr == p) {
#pragma unroll
        for (int ti = 0; ti < 4; ++ti)
#pragma unroll
          for (int tj = 0; tj < 4; ++tj) {
            int j  = wc * 64 + tj * 16 + lr;
            int Jl = ti * 16 + kq * 4;
            uint2 pk;
            pk.x = pk2(e[ti][tj][0], e[ti][tj][1]);
            pk.y = pk2(e[ti][tj][2], e[ti][tj][3]);
            *(uint2*)&lds[EO + j * 72 + Jl] = pk;
          }
      }
      __syncthreads();
      if (p == 0 && t < 128) denom[t] += cs[t] + cs[128 + t];
#pragma unroll
      for (int ks = 0; ks < 2; ++ks) {
        short8 ea[2], vf[2];
#pragma unroll
        for (int tr = 0; tr < 2; ++tr)
          ea[tr] = *(const short8*)&lds[EO + (wv * 32 + tr * 16 + lr) * 72 + ks * 32 + kq * 8];
#pragma unroll
        for (int tm = 0; tm < 2; ++tm)
          vf[tm] = *(const short8*)&lds[VtO + (tm * 16 + lr) * 136 + p * 64 + ks * 32 + kq * 8];
#pragma unroll
        for (int tr = 0; tr < 2; ++tr)
#pragma unroll
          for (int tm = 0; tm < 2; ++tm)
            o[tr][tm] = __builtin_amdgcn_mfma_f32_16x16x32_bf16(ea[tr], vf[tm], o[tr][tm], 0, 0, 0);
      }
    }
  }
  __syncthreads();

#pragma unroll
  for (int tr = 0; tr < 2; ++tr)
#pragma unroll
    for (int r = 0; r < 4; ++r) {
      int row = wv * 32 + tr * 16 + kq * 4 + r;
      float rinv = 1.f / denom[row];
#pragma unroll
      for (int tm = 0; tm < 2; ++tm)
        lds[row * 40 + tm * 16 + lr] = (short)f2bf(o[tr][tm][r] * rinv);
    }
  __syncthreads();
  if (LAYOUT == 1) {
    // PA[h][i][j][m]: contiguous 8KB per block
    const size_t base = ((size_t)(h * 128 + ii) * 256 + half * 128) * 32;
#pragma unroll
    for (int u = 0; u < 2; ++u) {
      int idx = t + u * 256;
      int jl = idx >> 2, mg = idx & 3;
      uint4 vv = *(const uint4*)&lds[jl * 40 + mg * 8];
      *(uint4*)(PA + base + jl * 32 + mg * 8) = vv;
    }
  } else {
#pragma unroll
    for (int u = 0; u < 2; ++u) {
      int idx = t + u * 256;
      int jl = idx >> 2, mg = idx & 3;
      uint4 vv = *(const uint4*)&lds[jl * 40 + mg * 8];
      *(uint4*)(PA + ((size_t)(ii * Pp + half * 128 + jl) * OUTC + h * 32 + mg * 8)) = vv;
    }
  }
}

// ---------------------------------------------------------------------------
extern "C" void kernel_launch(void* const* d_in, const int* in_sizes, int n_in,
                              void* d_out, int out_size, void* d_ws, size_t ws_size,
                              hipStream_t stream) {
  const float* x  = (const float*)d_in[0];
  const float* Wt = (const float*)d_in[1];
  const float* Wp = (const float*)d_in[2];
  const float* W1 = (const float*)d_in[3];
  const float* b1 = (const float*)d_in[4];
  const float* W2 = (const float*)d_in[5];
  const float* b2 = (const float*)d_in[6];
  float* out = (float*)d_out;
  short* ws  = (short*)d_ws;

  const size_t fixedH = 8388608 + 16777216 + 393216 + 786432 + 1048576 + 1048576
                      + 262144 + 1024 + 4194304 + 65536;
  size_t availH = ws_size / 2;
  size_t chF; int JC, IC;
  if      (availH >= fixedH + 50331648) { chF = 50331648; JC = 256; IC = 128; }
  else if (availH >= fixedH + 12582912) { chF = 12582912; JC = 64;  IC = 32;  }
  else if (availH >= fixedH + 6291456)  { chF = 6291456;  JC = 32;  IC = 16;  }
  else                                  { chF = 3145728;  JC = 16;  IC = 8;   }
  short* CH  = ws;
  short* xbf = CH + chF;
  short* At  = xbf + 8388608;
  short* B1t = At + 16777216;
  short* B2t = B1t + 393216;
  short* W1b = B2t + 786432;      // W1 as bf16 row-major (512 x 2048)
  short* W2t = W1b + 1048576;     // W2^T bf16 (512 x 2048)
  short* Wct = W2t + 1048576;     // (W1@W2)^T bf16 (512 x 512): Wct[o][k]
  float* bcF   = (float*)(Wct + 262144);                   // 512 fp32
  float* partF = (float*)(Wct + 262144 + 1024);            // 8 x 512 x 512 fp32
  float* bcP   = (float*)(Wct + 262144 + 1024 + 4194304);  // 64 x 512 fp32
  const int jcS = __builtin_ctz((unsigned)JC);
  const int icS = __builtin_ctz((unsigned)IC);

  conv_x<<<4096, 256, 0, stream>>>(x, xbf);
  conv_x<<<512, 256, 0, stream>>>(W1, W1b);
  transpose_to_bf16<<<dim3(8, 4, 3), 256, 0, stream>>>(Wt, B1t, 256, 512);
  repack_b2t<<<3072, 256, 0, stream>>>(Wp, B2t);
  transpose_to_bf16<<<dim3(8, 32, 1), 256, 0, stream>>>(W2, W2t, 2048, 512);

  // MLP is linear (no activation): fold W1@W2 -> Wc, b1@W2+b2 -> bc.
  wc_splitk<<<dim3(4, 4, 8), 256, 0, stream>>>(W2t, W1b, partF);
  wc_reduce<<<1024, 256, 0, stream>>>(partF, Wct);
  bc_partial<<<64, 256, 0, stream>>>(b1, W2, bcP);
  bc_finish<<<2, 256, 0, stream>>>(bcP, b2, bcF);

  if (JC == 256) {
    // Temporal QKV: retiled (AMAP=3) -> contiguous staged writes (EPI=3).
    gemm_mfma<256, 1536, 3, 3, 0><<<dim3(12, 256), 256, 0, stream>>>(xbf, B1t, CH, nullptr, 0, 0, 256);
    // Temporal attn -> T_out[h][jj][i][m] (head-major, contiguous writes).
    temporal_attn_mfma<1><<<Hh * 256, 256, 0, stream>>>(CH, At, 0, 8);
    // Point QKV: A = T_out via AMAP=5 (head-major K), EPI=2 point layout.
    gemm_mfma<512, 1536, 5, 2, 0><<<dim3(12, 256), 256, 0, stream>>>(At, B2t, CH, nullptr, 0, 0, 128);
    // Point attn -> PA[h][i][j][m] (head-major, contiguous writes).
    point_attn_mfma<1><<<Hh * 128 * 2, 256, 0, stream>>>(CH, At, 7);
    // Fused MLP: A = PA via AMAP=4 (head-major K), fp32 out + bias.
    gemm_mfma<512, 512, 4, 0, 1><<<dim3(4, 256), 256, 0, stream>>>(At, Wct, out, bcF, 0, 0, 0);
  } else {
    for (int j0 = 0; j0 < Pp; j0 += JC) {
      gemm_mfma<256, 1536, 1, 1, 0><<<dim3(12, JC), 256, 0, stream>>>(xbf, B1t, CH, nullptr, j0, jcS, JC);
      temporal_attn_mfma<0><<<Hh * JC, 256, 0, stream>>>(CH, At, j0, jcS);
    }
    for (int i0 = 0; i0 < Nf; i0 += IC) {
      short* Arows = At + (size_t)i0 * Pp * OUTC;
      gemm_mfma<512, 1536, 0, 2, 0><<<dim3(12, IC * 2), 256, 0, stream>>>(Arows, B2t, CH, nullptr, 0, 0, IC);
      point_attn_mfma<0><<<Hh * IC * 2, 256, 0, stream>>>(CH, Arows, icS);
    }
    gemm_mfma<512, 512, 0, 0, 1><<<dim3(4, 256), 256, 0, stream>>>(At, Wct, out, bcF, 0, 0, 0);
  }
}

// Round 10
// 351.537 us; speedup vs baseline: 1.0535x; 1.0531x over previous
//
#include <hip/hip_runtime.h>
#include <cstddef>
#include <cstdint>

constexpr int Nf = 128, Pp = 256, Dd = 256, Hh = 16, Mm = 32;
constexpr int OUTC = 512, HID = 2048, C3 = 1536;

typedef short short8 __attribute__((ext_vector_type(8)));   // 8 bf16 (4 VGPRs)
typedef float f32x4 __attribute__((ext_vector_type(4)));    // 4 fp32 acc

// fp32 -> bf16 round-to-nearest-even (scalar sites)
__device__ inline unsigned short f2bf(float f) {
  unsigned u = __float_as_uint(f);
  u += 0x7fffu + ((u >> 16) & 1u);
  return (unsigned short)(u >> 16);
}
// packed pair via HW cvt (RNE), 1 op per 2 values (T12 recipe)
__device__ inline unsigned pk2(float a, float b) {
  unsigned r;
  asm("v_cvt_pk_bf16_f32 %0, %1, %2" : "=v"(r) : "v"(a), "v"(b));
  return r;
}

// ---------------------------------------------------------------------------
__global__ __launch_bounds__(256) void conv_x(const float* __restrict__ x,
                                              short* __restrict__ xb) {
  int idx = blockIdx.x * 256 + threadIdx.x;
  const float4* s = (const float4*)x + (size_t)idx * 2;
  float4 a = s[0], c = s[1];
  uint4 o;
  o.x = pk2(a.x, a.y); o.y = pk2(a.z, a.w);
  o.z = pk2(c.x, c.y); o.w = pk2(c.z, c.w);
  ((uint4*)xb)[idx] = o;
}

// Generic coalesced transpose: in (R x C fp32, slice z) -> out (C x R bf16).
__global__ __launch_bounds__(256) void transpose_to_bf16(const float* __restrict__ in,
                                                         short* __restrict__ out,
                                                         int R, int C) {
  __shared__ float tile[64 * 65];
  const int t = threadIdx.x;
  const int rb = blockIdx.y * 64, cb = blockIdx.x * 64;
  const size_t sl = (size_t)blockIdx.z * R * C;
#pragma unroll
  for (int u = 0; u < 4; ++u) {
    int r = (t >> 4) + u * 16, c4 = (t & 15) * 4;
    float4 v = *(const float4*)(in + sl + (size_t)(rb + r) * C + cb + c4);
    tile[r * 65 + c4 + 0] = v.x;
    tile[r * 65 + c4 + 1] = v.y;
    tile[r * 65 + c4 + 2] = v.z;
    tile[r * 65 + c4 + 3] = v.w;
  }
  __syncthreads();
#pragma unroll
  for (int u = 0; u < 2; ++u) {
    int id = t + u * 256;
    int n = id >> 3, kg = id & 7;
    float a[8];
#pragma unroll
    for (int q = 0; q < 8; ++q) a[q] = tile[(kg * 8 + q) * 65 + n];
    uint4 o;
    o.x = pk2(a[0], a[1]); o.y = pk2(a[2], a[3]);
    o.z = pk2(a[4], a[5]); o.w = pk2(a[6], a[7]);
    *(uint4*)(out + sl + (size_t)(cb + n) * R + rb + kg * 8) = o;
  }
}

// B2t[c][k], k = HH*32+MM (1536 x 512)
__global__ void repack_b2t(const float* __restrict__ Wp, short* __restrict__ B2t) {
  int idx = blockIdx.x * 256 + threadIdx.x;  // 786432
  int c = idx >> 9, k = idx & 511;
  int w = c >> 9, h = (c >> 5) & 15, m = c & 31;
  int HH = k >> 5, MM = k & 31;
  B2t[idx] = (short)f2bf(Wp[(((w * Hh + h) * Mm + m) * Hh + HH) * Mm + MM]);
}

// ---------------------------------------------------------------------------
// MLP collapse helpers (run once; small).
__global__ __launch_bounds__(256) void wc_splitk(const short* __restrict__ A,   // W2t: 512 x 2048
                                                 const short* __restrict__ Bt,  // W1 bf16: 512 x 2048
                                                 float* __restrict__ part) {
  __shared__ short As[128 * 32];
  __shared__ short Bs[128 * 32];
  const int t = threadIdx.x;
  const int wv = t >> 6, ln = t & 63;
  const int wr = wv >> 1, wc = wv & 1;
  const int lr = ln & 15, kq = ln >> 4;
  const int row0 = blockIdx.y * 128, col0 = blockIdx.x * 128;
  const int k0 = blockIdx.z * 256;

  f32x4 acc[4][4];
#pragma unroll
  for (int i = 0; i < 4; ++i)
#pragma unroll
    for (int j = 0; j < 4; ++j) acc[i][j] = {0.f, 0.f, 0.f, 0.f};

  for (int kt = k0; kt < k0 + 256; kt += 32) {
#pragma unroll
    for (int u = 0; u < 2; ++u) {
      int seg = wv * 128 + u * 64 + ln;
      int r = seg >> 2, kg = seg & 3;
      const short* gp = A + (size_t)(row0 + r) * HID + kt + kg * 8;
      __builtin_amdgcn_global_load_lds(
          (const __attribute__((address_space(1))) void*)gp,
          (__attribute__((address_space(3))) void*)&As[(wv * 128 + u * 64) * 8], 16, 0, 0);
    }
#pragma unroll
    for (int u = 0; u < 2; ++u) {
      int seg = wv * 128 + u * 64 + ln;
      int r = seg >> 2, kg = seg & 3;
      const short* gp = Bt + (size_t)(col0 + r) * HID + kt + kg * 8;
      __builtin_amdgcn_global_load_lds(
          (const __attribute__((address_space(1))) void*)gp,
          (__attribute__((address_space(3))) void*)&Bs[(wv * 128 + u * 64) * 8], 16, 0, 0);
    }
    __syncthreads();
    short8 a[4], b[4];
#pragma unroll
    for (int ti = 0; ti < 4; ++ti)
      a[ti] = *(const short8*)&As[(wr * 64 + ti * 16 + lr) * 32 + kq * 8];
#pragma unroll
    for (int tj = 0; tj < 4; ++tj)
      b[tj] = *(const short8*)&Bs[(wc * 64 + tj * 16 + lr) * 32 + kq * 8];
#pragma unroll
    for (int ti = 0; ti < 4; ++ti)
#pragma unroll
      for (int tj = 0; tj < 4; ++tj)
        acc[ti][tj] = __builtin_amdgcn_mfma_f32_16x16x32_bf16(a[ti], b[tj], acc[ti][tj], 0, 0, 0);
    __syncthreads();
  }

#pragma unroll
  for (int tj = 0; tj < 4; ++tj) {
    int gcol = col0 + wc * 64 + tj * 16 + lr;
#pragma unroll
    for (int ti = 0; ti < 4; ++ti)
#pragma unroll
      for (int rg = 0; rg < 4; ++rg) {
        int grow = row0 + wr * 64 + ti * 16 + kq * 4 + rg;
        part[((size_t)blockIdx.z * 512 + grow) * 512 + gcol] = acc[ti][tj][rg];
      }
  }
}

__global__ __launch_bounds__(256) void wc_reduce(const float* __restrict__ part,
                                                 short* __restrict__ Wct) {
  int idx = blockIdx.x * 256 + threadIdx.x;  // 262144
  float s = 0.f;
#pragma unroll
  for (int z = 0; z < 8; ++z) s += part[(size_t)z * 262144 + idx];
  Wct[idx] = (short)f2bf(s);
}

__global__ __launch_bounds__(256) void bc_partial(const float* __restrict__ b1,
                                                  const float* __restrict__ W2,
                                                  float* __restrict__ part) {
  const int z = blockIdx.x;       // 64 chunks of 32 h
  const int t = threadIdx.x;
  float s0 = 0.f, s1 = 0.f;
#pragma unroll
  for (int hh = 0; hh < 32; ++hh) {
    int h = z * 32 + hh;
    float bv = b1[h];
    s0 += bv * W2[(size_t)h * OUTC + t];
    s1 += bv * W2[(size_t)h * OUTC + t + 256];
  }
  part[z * OUTC + t] = s0;
  part[z * OUTC + t + 256] = s1;
}

__global__ __launch_bounds__(256) void bc_finish(const float* __restrict__ part,
                                                 const float* __restrict__ b2,
                                                 float* __restrict__ bc) {
  int o = blockIdx.x * 256 + threadIdx.x;  // 512
  float s = b2[o];
#pragma unroll
  for (int z = 0; z < 64; ++z) s += part[z * OUTC + o];
  bc[o] = s;
}

// ---------------------------------------------------------------------------
// bf16 MFMA GEMM, counted-vmcnt 2-deep pipeline + LDS XOR swizzle (verified r5).
// AMAP: 0 = linear rows; 1 = (i,jj) chunked; 3 = temporal retile;
//       4 = head-major A [k>>5][row][32]     (arow = row)
//       5 = head-major A [k>>5][j][i][32]    (arow = (row&255)*128 + (row>>8))
// Head stride for AMAP 4/5 = 32768*32 = 1048576 shorts.
template <int KDIM, int NCOLS, int AMAP, int EPI, int OUTT>
__global__ __launch_bounds__(256) void gemm_mfma(const short* __restrict__ A,
                                                 const short* __restrict__ Bt,
                                                 void* __restrict__ Cv,
                                                 const float* __restrict__ bias,
                                                 int j0, int pshift, int pc) {
  __shared__ __align__(16) short SH[16384];   // As[2] | Bs[2]; reused as outb
  const int t = threadIdx.x;
  const int wv = t >> 6, ln = t & 63;
  const int wr = wv >> 1, wc = wv & 1;
  const int lr = ln & 15, kq = ln >> 4;

  constexpr int NBX = NCOLS / 128;
  constexpr int NT = KDIM / 32;
  int lin = blockIdx.y * NBX + blockIdx.x;
  int nblk = gridDim.x * gridDim.y;
  int bx, by;
  if ((nblk & 7) == 0) {
    int per = nblk >> 3;
    int id = (lin & 7) * per + (lin >> 3);   // bijective; groups rows per XCD
    bx = id % NBX; by = id / NBX;
  } else {
    bx = blockIdx.x; by = blockIdx.y;
  }
  const int row0 = by * 128, col0 = bx * 128;

  // Staging geometry (constant per thread).
  const int seg0 = wv * 128 + ln;
  const int seg1 = wv * 128 + 64 + ln;
  const int r0 = seg0 >> 2, r1 = seg1 >> 2;
  const int kg0 = (seg0 & 3) ^ ((r0 >> 1) & 3);   // pre-swizzled source chunk
  const int kg1 = (seg1 & 3) ^ ((r1 >> 1) & 3);
  size_t aoff0, aoff1;   // kt-independent part of the A offset
  {
    int rr = row0 + r0;
    if (AMAP == 0)      aoff0 = (size_t)rr * KDIM;
    else if (AMAP == 3) aoff0 = (size_t)(((rr & 127) << 8) + (rr >> 7)) * KDIM;
    else if (AMAP == 4) aoff0 = (size_t)rr * 32;
    else if (AMAP == 5) aoff0 = (size_t)(((rr & 255) << 7) + (rr >> 8)) * 32;
    else { int i = rr >> pshift, jj = rr & (pc - 1); aoff0 = (size_t)((i << 8) + j0 + jj) * KDIM; }
    rr = row0 + r1;
    if (AMAP == 0)      aoff1 = (size_t)rr * KDIM;
    else if (AMAP == 3) aoff1 = (size_t)(((rr & 127) << 8) + (rr >> 7)) * KDIM;
    else if (AMAP == 4) aoff1 = (size_t)rr * 32;
    else if (AMAP == 5) aoff1 = (size_t)(((rr & 255) << 7) + (rr >> 8)) * 32;
    else { int i = rr >> pshift, jj = rr & (pc - 1); aoff1 = (size_t)((i << 8) + j0 + jj) * KDIM; }
  }
  const size_t brow0 = (size_t)(col0 + r0), brow1 = (size_t)(col0 + r1);

  auto stage = [&](int buf, int tk) {
    const int kt = tk * 32;
    const size_t kb = (AMAP >= 4) ? (size_t)tk * 1048576 : (size_t)kt;
    __builtin_amdgcn_global_load_lds(
        (const __attribute__((address_space(1))) void*)(A + aoff0 + kb + kg0 * 8),
        (__attribute__((address_space(3))) void*)&SH[buf * 4096 + (wv * 128) * 8], 16, 0, 0);
    __builtin_amdgcn_global_load_lds(
        (const __attribute__((address_space(1))) void*)(A + aoff1 + kb + kg1 * 8),
        (__attribute__((address_space(3))) void*)&SH[buf * 4096 + (wv * 128 + 64) * 8], 16, 0, 0);
    __builtin_amdgcn_global_load_lds(
        (const __attribute__((address_space(1))) void*)(Bt + brow0 * KDIM + kt + kg0 * 8),
        (__attribute__((address_space(3))) void*)&SH[8192 + buf * 4096 + (wv * 128) * 8], 16, 0, 0);
    __builtin_amdgcn_global_load_lds(
        (const __attribute__((address_space(1))) void*)(Bt + brow1 * KDIM + kt + kg1 * 8),
        (__attribute__((address_space(3))) void*)&SH[8192 + buf * 4096 + (wv * 128 + 64) * 8], 16, 0, 0);
  };

  f32x4 acc[4][4];
#pragma unroll
  for (int i = 0; i < 4; ++i)
#pragma unroll
    for (int j = 0; j < 4; ++j) acc[i][j] = {0.f, 0.f, 0.f, 0.f};

  const int slot = kq ^ ((lr >> 1) & 3);   // swizzled fragment slot

  stage(0, 0);
  stage(1, 1);
  asm volatile("s_waitcnt vmcnt(4)" ::: "memory");
  __builtin_amdgcn_s_barrier();

  for (int tk = 0; tk < NT; ++tk) {
    const int cur = tk & 1;
    short8 a[4], b[4];
#pragma unroll
    for (int ti = 0; ti < 4; ++ti)
      a[ti] = *(const short8*)&SH[cur * 4096 + (wr * 64 + ti * 16 + lr) * 32 + slot * 8];
#pragma unroll
    for (int tj = 0; tj < 4; ++tj)
      b[tj] = *(const short8*)&SH[8192 + cur * 4096 + (wc * 64 + tj * 16 + lr) * 32 + slot * 8];
    __builtin_amdgcn_sched_barrier(0);
    asm volatile("s_waitcnt lgkmcnt(0)" ::: "memory");
    __builtin_amdgcn_sched_barrier(0);
    if (tk + 1 < NT) {
      __builtin_amdgcn_s_barrier();        // all waves done reading buf[cur]
      if (tk + 2 < NT) stage(cur, tk + 2);
    }
#pragma unroll
    for (int ti = 0; ti < 4; ++ti)
#pragma unroll
      for (int tj = 0; tj < 4; ++tj)
        acc[ti][tj] = __builtin_amdgcn_mfma_f32_16x16x32_bf16(a[ti], b[tj], acc[ti][tj], 0, 0, 0);
    if (tk + 1 < NT) {
      if (tk + 2 < NT) {
        asm volatile("s_waitcnt vmcnt(4)" ::: "memory");
      } else {
        asm volatile("s_waitcnt vmcnt(0)" ::: "memory");
      }
      __builtin_amdgcn_s_barrier();
      __builtin_amdgcn_sched_barrier(0);
    }
  }

  if (EPI == 0 || EPI == 1) {
#pragma unroll
    for (int tj = 0; tj < 4; ++tj) {
      int gcol = col0 + wc * 64 + tj * 16 + lr;
      float bv = (EPI == 0) ? bias[gcol] : 0.f;
#pragma unroll
      for (int ti = 0; ti < 4; ++ti) {
#pragma unroll
        for (int rg = 0; rg < 4; ++rg) {
          int grow = row0 + wr * 64 + ti * 16 + kq * 4 + rg;
          float val = acc[ti][tj][rg];
          if (EPI == 0) {
            val += bv;
            if (OUTT == 0) ((short*)Cv)[(size_t)grow * NCOLS + gcol] = (short)f2bf(val);
            else           ((float*)Cv)[(size_t)grow * NCOLS + gcol] = val;
          } else {
            int w = gcol >> 9, h = (gcol >> 5) & 15, m = gcol & 31;
            int i = grow >> pshift, jj = grow & (pc - 1);
            size_t addr = (((size_t)(w * Hh + h) * pc + jj) * Nf + i) * Mm + m;
            ((short*)Cv)[addr] = (short)f2bf(val);
          }
        }
      }
    }
  } else {
    // LDS-staged coalesced epilogue (EPI==2 point layout, EPI==3 temporal).
    __builtin_amdgcn_s_barrier();   // all waves done with SH (reads complete)
#pragma unroll
    for (int ti = 0; ti < 4; ++ti)
#pragma unroll
      for (int tj = 0; tj < 4; ++tj) {
        int c = wc * 64 + tj * 16 + lr;
        int q = c >> 5, m = c & 31;
#pragma unroll
        for (int rg = 0; rg < 4; ++rg) {
          int g = wr * 64 + ti * 16 + kq * 4 + rg;
          SH[q * 4096 + g * 32 + (m ^ ((g & 4) << 2))] = (short)f2bf(acc[ti][tj][rg]);
        }
      }
    __syncthreads();
#pragma unroll
    for (int u = 0; u < 8; ++u) {
      int id = u * 256 + t;
      int q = id >> 9, rem = id & 511, g = rem >> 2, mc = (rem & 3) * 8;
      uint4 v = *(const uint4*)&SH[q * 4096 + g * 32 + (mc ^ ((g & 4) << 2))];
      int gc = col0 + q * 32;
      int w = gc >> 9, h = (gc >> 5) & 15;
      size_t base;
      if (EPI == 3) base = ((size_t)(w * Hh + h) * 256 + (row0 >> 7)) * 4096;
      else          base = (((size_t)(w * Hh + h) * pc + (row0 >> 8)) * 256 + (row0 & 255)) * 32;
      *(uint4*)((short*)Cv + base + g * 32 + mc) = v;
    }
  }
}

// ---------------------------------------------------------------------------
// Temporal attention, MFMA. r10: no min-waves bound (r8's (256,4) forced
// unified VGPR+AGPR <=128 -> scratch spills -> +80MB HBM writes); P packed
// to bf16 during normalize so e[4][4] dies before PV phases (reg-class cut).
template <int LAYOUT>
__global__ __launch_bounds__(256) void temporal_attn_mfma(const short* __restrict__ T,
                                                          short* __restrict__ At,
                                                          int j0, int jcShift) {
  constexpr int KsO = 0, VtO = 4096, WtO = 8448, RsO = 17664;
  __shared__ __align__(16) short lds[18176];
  float* rs = (float*)&lds[RsO];
  const int JC = 1 << jcShift;
  const int h  = blockIdx.x >> jcShift;
  const int jj = blockIdx.x & (JC - 1);
  const int t  = threadIdx.x;
  const int wv = t >> 6, ln = t & 63;
  const int wr = wv >> 1, wc = wv & 1;
  const int lr = ln & 15, kq = ln >> 4;
  const size_t WC = (size_t)(Hh << jcShift) * 4096;
  const short* qb = T + (size_t)(h * JC + jj) * 4096;
  const short* kb = qb + WC;
  const short* vb = qb + 2 * WC;

  const int lnoff = (ln >> 2) * 32 + (((ln & 3) ^ ((ln >> 3) & 3)) * 8);
  const int qkslot = (kq ^ ((lr >> 1) & 3)) * 8;   // swizzled fragment slot

  // Q fragments direct from global (row-major 128x32, 16B-aligned rows).
  short8 af[4];
#pragma unroll
  for (int ti = 0; ti < 4; ++ti)
    af[ti] = *(const short8*)(qb + (wr * 64 + ti * 16 + lr) * 32 + kq * 8);

#pragma unroll
  for (int u = 0; u < 2; ++u) {
    int seg = wv * 2 + u;
    __builtin_amdgcn_global_load_lds(
        (const __attribute__((address_space(1))) void*)(kb + seg * 512 + lnoff),
        (__attribute__((address_space(3))) void*)&lds[KsO + seg * 512], 16, 0, 0);
  }
#pragma unroll
  for (int u = 0; u < 2; ++u) {
    int idx = t + u * 256;
    int I = idx >> 2, g = idx & 3;
    uint4 v = *(const uint4*)(vb + idx * 8);
    unsigned w0 = v.x, w1 = v.y, w2 = v.z, w3 = v.w;
    if (g & 1) { unsigned tp = w0; w0 = w1; w1 = w2; w2 = w3; w3 = tp; }
    if (g & 2) { unsigned t0 = w0, t1 = w1; w0 = w2; w1 = w3; w2 = t0; w3 = t1; }
    const unsigned wa[4] = {w0, w1, w2, w3};
    int m0 = g * 8, g2 = g * 2;
#pragma unroll
    for (int k = 0; k < 4; ++k) {
      int q = (2 * k + g2) & 7;
      lds[VtO + (m0 + q) * 136 + I]     = (short)(wa[k] & 0xffffu);
      lds[VtO + (m0 + q + 1) * 136 + I] = (short)(wa[k] >> 16);
    }
  }
  __syncthreads();

  short8 bf[4];
#pragma unroll
  for (int tj = 0; tj < 4; ++tj)
    bf[tj] = *(const short8*)&lds[KsO + (wc * 64 + tj * 16 + lr) * 32 + qkslot];
  f32x4 e[4][4];
#pragma unroll
  for (int ti = 0; ti < 4; ++ti)
#pragma unroll
    for (int tj = 0; tj < 4; ++tj) e[ti][tj] = {0.f, 0.f, 0.f, 0.f};
#pragma unroll
  for (int ti = 0; ti < 4; ++ti)
#pragma unroll
    for (int tj = 0; tj < 4; ++tj)
      e[ti][tj] = __builtin_amdgcn_mfma_f32_16x16x32_bf16(af[ti], bf[tj], e[ti][tj], 0, 0, 0);

  float part[4][4];
#pragma unroll
  for (int ti = 0; ti < 4; ++ti)
#pragma unroll
    for (int r = 0; r < 4; ++r) {
      float p = 0.f;
#pragma unroll
      for (int tj = 0; tj < 4; ++tj) {
        float ex = __expf(e[ti][tj][r]);
        e[ti][tj][r] = ex;
        p += ex;
      }
      part[ti][r] = p;
    }
#pragma unroll
  for (int msk = 1; msk <= 8; msk <<= 1)
#pragma unroll
    for (int ti = 0; ti < 4; ++ti)
#pragma unroll
      for (int r = 0; r < 4; ++r)
        part[ti][r] += __shfl_xor(part[ti][r], msk, 64);
  if (lr == 0) {
#pragma unroll
    for (int ti = 0; ti < 4; ++ti)
#pragma unroll
      for (int r = 0; r < 4; ++r)
        rs[wc * 128 + wr * 64 + ti * 16 + kq * 4 + r] = part[ti][r];
  }
  __syncthreads();

  // normalize + pack P to bf16 in one pass (e dies here -> lower reg class)
  uint2 pkW[4][4];
#pragma unroll
  for (int ti = 0; ti < 4; ++ti) {
    float inv[4];
#pragma unroll
    for (int r = 0; r < 4; ++r) {
      int I = wr * 64 + ti * 16 + kq * 4 + r;
      inv[r] = 1.f / (rs[I] + rs[128 + I]);
    }
#pragma unroll
    for (int tj = 0; tj < 4; ++tj) {
      pkW[ti][tj].x = pk2(e[ti][tj][0] * inv[0], e[ti][tj][1] * inv[1]);
      pkW[ti][tj].y = pk2(e[ti][tj][2] * inv[2], e[ti][tj][3] * inv[3]);
    }
  }

  // J-half-split PV: phase p uses Wt rows [i][Ib'=0..63] for I in [p*64,(p+1)*64)
  f32x4 o[2][2];
#pragma unroll
  for (int tr = 0; tr < 2; ++tr)
#pragma unroll
    for (int tm = 0; tm < 2; ++tm) o[tr][tm] = {0.f, 0.f, 0.f, 0.f};
#pragma unroll
  for (int p = 0; p < 2; ++p) {
    if (p) __syncthreads();            // phase-0 reads complete before overwrite
    if (wr == p) {
#pragma unroll
      for (int ti = 0; ti < 4; ++ti)
#pragma unroll
        for (int tj = 0; tj < 4; ++tj) {
          int i = wc * 64 + tj * 16 + lr;
          int Ib = ti * 16 + kq * 4;
          *(uint2*)&lds[WtO + i * 72 + Ib] = pkW[ti][tj];
        }
    }
    __syncthreads();
#pragma unroll
    for (int ks = 0; ks < 2; ++ks) {
      short8 ea[2], vf[2];
#pragma unroll
      for (int tr = 0; tr < 2; ++tr)
        ea[tr] = *(const short8*)&lds[WtO + (wv * 32 + tr * 16 + lr) * 72 + ks * 32 + kq * 8];
#pragma unroll
      for (int tm = 0; tm < 2; ++tm)
        vf[tm] = *(const short8*)&lds[VtO + (tm * 16 + lr) * 136 + p * 64 + ks * 32 + kq * 8];
#pragma unroll
      for (int tr = 0; tr < 2; ++tr)
#pragma unroll
        for (int tm = 0; tm < 2; ++tm)
          o[tr][tm] = __builtin_amdgcn_mfma_f32_16x16x32_bf16(ea[tr], vf[tm], o[tr][tm], 0, 0, 0);
    }
  }
#pragma unroll
  for (int tr = 0; tr < 2; ++tr)
#pragma unroll
    for (int tm = 0; tm < 2; ++tm)
#pragma unroll
      for (int r = 0; r < 4; ++r) {
        int row = wv * 32 + tr * 16 + kq * 4 + r;
        lds[row * 40 + tm * 16 + lr] = (short)f2bf(o[tr][tm][r]);
      }
  __syncthreads();
  if (LAYOUT == 1) {
    // T_out[h][jj][i][m]: contiguous 8KB per block
    const size_t base = (size_t)(h * 256 + j0 + jj) * 4096;
#pragma unroll
    for (int u = 0; u < 2; ++u) {
      int idx = t + u * 256;
      int i = idx >> 2, mg = idx & 3;
      uint4 vv = *(const uint4*)&lds[i * 40 + mg * 8];
      *(uint4*)(At + base + i * 32 + mg * 8) = vv;
    }
  } else {
#pragma unroll
    for (int u = 0; u < 2; ++u) {
      int idx = t + u * 256;
      int i = idx >> 2, mg = idx & 3;
      uint4 vv = *(const uint4*)&lds[i * 40 + mg * 8];
      *(uint4*)(At + ((size_t)(i * Pp + j0 + jj) * OUTC + h * 32 + mg * 8)) = vv;
    }
  }
}

// ---------------------------------------------------------------------------
// Point attention, MFMA. r10: no min-waves bound (kill r8 spills); exp+pack
// fused per QK^T tile so no fp32 P array is ever live (pkE = 32 regs).
template <int LAYOUT>
__global__ __launch_bounds__(256) void point_attn_mfma(const short* __restrict__ P,
                                                       short* __restrict__ PA,
                                                       int icShift) {
  constexpr int KsO = 0, VtO = 4096, EO = 8448, CsO = 17664;
  __shared__ __align__(16) short lds[18432];
  float* cs    = (float*)&lds[CsO];
  float* denom = cs + 256;
  const int IC = 1 << icShift;
  const int bx = blockIdx.x;
  const int h    = bx >> (icShift + 1);
  const int rem  = bx & ((IC << 1) - 1);
  const int ii   = rem >> 1;
  const int half = rem & 1;
  const int t  = threadIdx.x;
  const int wv = t >> 6, ln = t & 63;
  const int wr = wv >> 1, wc = wv & 1;
  const int lr = ln & 15, kq = ln >> 4;
  const size_t WC = (size_t)(Hh << icShift) * 8192;
  const short* qb = P + (size_t)(h * IC + ii) * 8192 + half * 4096;
  const short* kb = P + WC + (size_t)(h * IC + ii) * 8192;
  const short* vb = kb + WC;

  const int lnoff = (ln >> 2) * 32 + (((ln & 3) ^ ((ln >> 3) & 3)) * 8);
  const int qkslot = (kq ^ ((lr >> 1) & 3)) * 8;

  // Q fragments direct from global (row-major 128x32, 16B-aligned rows).
  short8 bf[4];
#pragma unroll
  for (int tj = 0; tj < 4; ++tj)
    bf[tj] = *(const short8*)(qb + (wc * 64 + tj * 16 + lr) * 32 + kq * 8);

  f32x4 o[2][2];
#pragma unroll
  for (int tr = 0; tr < 2; ++tr)
#pragma unroll
    for (int tm = 0; tm < 2; ++tm) o[tr][tm] = {0.f, 0.f, 0.f, 0.f};

  for (int chunk = 0; chunk < 2; ++chunk) {
    const int Jb = chunk * 128;
    if (chunk) __syncthreads();
#pragma unroll
    for (int u = 0; u < 2; ++u) {
      int seg = wv * 2 + u;
      __builtin_amdgcn_global_load_lds(
          (const __attribute__((address_space(1))) void*)(kb + Jb * 32 + seg * 512 + lnoff),
          (__attribute__((address_space(3))) void*)&lds[KsO + seg * 512], 16, 0, 0);
    }
    if (chunk == 0) {
      if (t < 128) denom[t] = 0.f;
    }
#pragma unroll
    for (int u = 0; u < 2; ++u) {
      int idx = t + u * 256;
      int Jl = idx >> 2, g = idx & 3;
      uint4 v = *(const uint4*)(vb + Jb * 32 + idx * 8);
      unsigned w0 = v.x, w1 = v.y, w2 = v.z, w3 = v.w;
      if (g & 1) { unsigned tp = w0; w0 = w1; w1 = w2; w2 = w3; w3 = tp; }
      if (g & 2) { unsigned t0 = w0, t1 = w1; w0 = w2; w1 = w3; w2 = t0; w3 = t1; }
      const unsigned wa[4] = {w0, w1, w2, w3};
      int m0 = g * 8, g2 = g * 2;
#pragma unroll
      for (int k = 0; k < 4; ++k) {
        int q = (2 * k + g2) & 7;
        lds[VtO + (m0 + q) * 136 + Jl]     = (short)(wa[k] & 0xffffu);
        lds[VtO + (m0 + q + 1) * 136 + Jl] = (short)(wa[k] >> 16);
      }
    }
    __syncthreads();

    short8 af[4];
#pragma unroll
    for (int ti = 0; ti < 4; ++ti)
      af[ti] = *(const short8*)&lds[KsO + (wr * 64 + ti * 16 + lr) * 32 + qkslot];

    // QK^T -> exp -> row-sum -> pack bf16, fused per tile (no fp32 P array).
    uint2 pkE[4][4];
    float cp[4] = {0.f, 0.f, 0.f, 0.f};
#pragma unroll
    for (int ti = 0; ti < 4; ++ti)
#pragma unroll
      for (int tj = 0; tj < 4; ++tj) {
        f32x4 ev = {0.f, 0.f, 0.f, 0.f};
        ev = __builtin_amdgcn_mfma_f32_16x16x32_bf16(af[ti], bf[tj], ev, 0, 0, 0);
        float e0 = __expf(ev[0]);
        float e1 = __expf(ev[1]);
        float e2 = __expf(ev[2]);
        float e3 = __expf(ev[3]);
        cp[tj] += e0; cp[tj] += e1; cp[tj] += e2; cp[tj] += e3;
        pkE[ti][tj].x = pk2(e0, e1);
        pkE[ti][tj].y = pk2(e2, e3);
      }
#pragma unroll
    for (int tj = 0; tj < 4; ++tj) {
      cp[tj] += __shfl_xor(cp[tj], 16, 64);
      cp[tj] += __shfl_xor(cp[tj], 32, 64);
    }
    if (kq == 0) {
#pragma unroll
      for (int tj = 0; tj < 4; ++tj)
        cs[wr * 128 + wc * 64 + tj * 16 + lr] = cp[tj];
    }

    // J-half-split PV: phase p stores E rows [j][Jl'=0..63] for Jl in
    // [p*64,(p+1)*64) (written by waves with wr==p), then PV with K=64.
#pragma unroll
    for (int p = 0; p < 2; ++p) {
      if (p) __syncthreads();          // phase-0 reads complete before overwrite
      if (wr == p) {
#pragma unroll
        for (int ti = 0; ti < 4; ++ti)
#pragma unroll
          for (int tj = 0; tj < 4; ++tj) {
            int j  = wc * 64 + tj * 16 + lr;
            int Jl = ti * 16 + kq * 4;
            *(uint2*)&lds[EO + j * 72 + Jl] = pkE[ti][tj];
          }
      }
      __syncthreads();
      if (p == 0 && t < 128) denom[t] += cs[t] + cs[128 + t];
#pragma unroll
      for (int ks = 0; ks < 2; ++ks) {
        short8 ea[2], vf[2];
#pragma unroll
        for (int tr = 0; tr < 2; ++tr)
          ea[tr] = *(const short8*)&lds[EO + (wv * 32 + tr * 16 + lr) * 72 + ks * 32 + kq * 8];
#pragma unroll
        for (int tm = 0; tm < 2; ++tm)
          vf[tm] = *(const short8*)&lds[VtO + (tm * 16 + lr) * 136 + p * 64 + ks * 32 + kq * 8];
#pragma unroll
        for (int tr = 0; tr < 2; ++tr)
#pragma unroll
          for (int tm = 0; tm < 2; ++tm)
            o[tr][tm] = __builtin_amdgcn_mfma_f32_16x16x32_bf16(ea[tr], vf[tm], o[tr][tm], 0, 0, 0);
      }
    }
  }
  __syncthreads();

#pragma unroll
  for (int tr = 0; tr < 2; ++tr)
#pragma unroll
    for (int r = 0; r < 4; ++r) {
      int row = wv * 32 + tr * 16 + kq * 4 + r;
      float rinv = 1.f / denom[row];
#pragma unroll
      for (int tm = 0; tm < 2; ++tm)
        lds[row * 40 + tm * 16 + lr] = (short)f2bf(o[tr][tm][r] * rinv);
    }
  __syncthreads();
  if (LAYOUT == 1) {
    // PA[h][i][j][m]: contiguous 8KB per block
    const size_t base = ((size_t)(h * 128 + ii) * 256 + half * 128) * 32;
#pragma unroll
    for (int u = 0; u < 2; ++u) {
      int idx = t + u * 256;
      int jl = idx >> 2, mg = idx & 3;
      uint4 vv = *(const uint4*)&lds[jl * 40 + mg * 8];
      *(uint4*)(PA + base + jl * 32 + mg * 8) = vv;
    }
  } else {
#pragma unroll
    for (int u = 0; u < 2; ++u) {
      int idx = t + u * 256;
      int jl = idx >> 2, mg = idx & 3;
      uint4 vv = *(const uint4*)&lds[jl * 40 + mg * 8];
      *(uint4*)(PA + ((size_t)(ii * Pp + half * 128 + jl) * OUTC + h * 32 + mg * 8)) = vv;
    }
  }
}

// ---------------------------------------------------------------------------
extern "C" void kernel_launch(void* const* d_in, const int* in_sizes, int n_in,
                              void* d_out, int out_size, void* d_ws, size_t ws_size,
                              hipStream_t stream) {
  const float* x  = (const float*)d_in[0];
  const float* Wt = (const float*)d_in[1];
  const float* Wp = (const float*)d_in[2];
  const float* W1 = (const float*)d_in[3];
  const float* b1 = (const float*)d_in[4];
  const float* W2 = (const float*)d_in[5];
  const float* b2 = (const float*)d_in[6];
  float* out = (float*)d_out;
  short* ws  = (short*)d_ws;

  const size_t fixedH = 8388608 + 16777216 + 393216 + 786432 + 1048576 + 1048576
                      + 262144 + 1024 + 4194304 + 65536;
  size_t availH = ws_size / 2;
  size_t chF; int JC, IC;
  if      (availH >= fixedH + 50331648) { chF = 50331648; JC = 256; IC = 128; }
  else if (availH >= fixedH + 12582912) { chF = 12582912; JC = 64;  IC = 32;  }
  else if (availH >= fixedH + 6291456)  { chF = 6291456;  JC = 32;  IC = 16;  }
  else                                  { chF = 3145728;  JC = 16;  IC = 8;   }
  short* CH  = ws;
  short* xbf = CH + chF;
  short* At  = xbf + 8388608;
  short* B1t = At + 16777216;
  short* B2t = B1t + 393216;
  short* W1b = B2t + 786432;      // W1 as bf16 row-major (512 x 2048)
  short* W2t = W1b + 1048576;     // W2^T bf16 (512 x 2048)
  short* Wct = W2t + 1048576;     // (W1@W2)^T bf16 (512 x 512): Wct[o][k]
  float* bcF   = (float*)(Wct + 262144);                   // 512 fp32
  float* partF = (float*)(Wct + 262144 + 1024);            // 8 x 512 x 512 fp32
  float* bcP   = (float*)(Wct + 262144 + 1024 + 4194304);  // 64 x 512 fp32
  const int jcS = __builtin_ctz((unsigned)JC);
  const int icS = __builtin_ctz((unsigned)IC);

  conv_x<<<4096, 256, 0, stream>>>(x, xbf);
  conv_x<<<512, 256, 0, stream>>>(W1, W1b);
  transpose_to_bf16<<<dim3(8, 4, 3), 256, 0, stream>>>(Wt, B1t, 256, 512);
  repack_b2t<<<3072, 256, 0, stream>>>(Wp, B2t);
  transpose_to_bf16<<<dim3(8, 32, 1), 256, 0, stream>>>(W2, W2t, 2048, 512);

  // MLP is linear (no activation): fold W1@W2 -> Wc, b1@W2+b2 -> bc.
  wc_splitk<<<dim3(4, 4, 8), 256, 0, stream>>>(W2t, W1b, partF);
  wc_reduce<<<1024, 256, 0, stream>>>(partF, Wct);
  bc_partial<<<64, 256, 0, stream>>>(b1, W2, bcP);
  bc_finish<<<2, 256, 0, stream>>>(bcP, b2, bcF);

  if (JC == 256) {
    // Temporal QKV: retiled (AMAP=3) -> contiguous staged writes (EPI=3).
    gemm_mfma<256, 1536, 3, 3, 0><<<dim3(12, 256), 256, 0, stream>>>(xbf, B1t, CH, nullptr, 0, 0, 256);
    // Temporal attn -> T_out[h][jj][i][m] (head-major, contiguous writes).
    temporal_attn_mfma<1><<<Hh * 256, 256, 0, stream>>>(CH, At, 0, 8);
    // Point QKV: A = T_out via AMAP=5 (head-major K), EPI=2 point layout.
    gemm_mfma<512, 1536, 5, 2, 0><<<dim3(12, 256), 256, 0, stream>>>(At, B2t, CH, nullptr, 0, 0, 128);
    // Point attn -> PA[h][i][j][m] (head-major, contiguous writes).
    point_attn_mfma<1><<<Hh * 128 * 2, 256, 0, stream>>>(CH, At, 7);
    // Fused MLP: A = PA via AMAP=4 (head-major K), fp32 out + bias.
    gemm_mfma<512, 512, 4, 0, 1><<<dim3(4, 256), 256, 0, stream>>>(At, Wct, out, bcF, 0, 0, 0);
  } else {
    for (int j0 = 0; j0 < Pp; j0 += JC) {
      gemm_mfma<256, 1536, 1, 1, 0><<<dim3(12, JC), 256, 0, stream>>>(xbf, B1t, CH, nullptr, j0, jcS, JC);
      temporal_attn_mfma<0><<<Hh * JC, 256, 0, stream>>>(CH, At, j0, jcS);
    }
    for (int i0 = 0; i0 < Nf; i0 += IC) {
      short* Arows = At + (size_t)i0 * Pp * OUTC;
      gemm_mfma<512, 1536, 0, 2, 0><<<dim3(12, IC * 2), 256, 0, stream>>>(Arows, B2t, CH, nullptr, 0, 0, IC);
      point_attn_mfma<0><<<Hh * IC * 2, 256, 0, stream>>>(CH, Arows, icS);
    }
    gemm_mfma<512, 512, 0, 0, 1><<<dim3(4, 256), 256, 0, stream>>>(At, Wct, out, bcF, 0, 0, 0);
  }
}